// Round 1
// baseline (9893.606 us; speedup 1.0000x reference)
//
#include <hip/hip_runtime.h>
#include <hip/hip_bf16.h>
#include <math.h>

// Model dims
#define LAYERS 5
#define DMODEL 1024
#define NH 16
#define NKV 8
#define HDIM 128
#define FFD 3072
#define SEQ 2048
#define GQA 2
#define RMS_EPS 1e-6f
#define ATT_SCALE 0.08838834764831845f  // 128^-0.5

// ---------------------------------------------------------------------------
// RoPE tables: cos/sin (T x 64), computed the way JAX does (fp32 angle product)
// but with double-accurate inv_freq and trig.
__global__ void rope_init_k(float* __restrict__ cosT, float* __restrict__ sinT) {
    int t = blockIdx.x;
    int j = threadIdx.x;  // 0..63
    double inv = pow(1.0e6, -((double)j) / 64.0);
    float angf = (float)t * (float)inv;     // fp32 product like JAX
    double ang = (double)angf;
    cosT[t * 64 + j] = (float)cos(ang);
    sinT[t * 64 + j] = (float)sin(ang);
}

// ---------------------------------------------------------------------------
// RMSNorm over D=1024. One block (256 thr) per row.
__global__ __launch_bounds__(256) void rms_k(const float* __restrict__ in,
                                             const float* __restrict__ w,
                                             float* __restrict__ out) {
    __shared__ float red[4];
    const int row = blockIdx.x;
    const int t = threadIdx.x;
    const float* p = in + (size_t)row * DMODEL;
    float4 v = *(const float4*)(p + t * 4);
    float ss = v.x * v.x + v.y * v.y + v.z * v.z + v.w * v.w;
#pragma unroll
    for (int off = 32; off >= 1; off >>= 1) ss += __shfl_xor(ss, off, 64);
    if ((t & 63) == 0) red[t >> 6] = ss;
    __syncthreads();
    float tot = red[0] + red[1] + red[2] + red[3];
    float scale = rsqrtf(tot * (1.0f / DMODEL) + RMS_EPS);
    float4 w4 = *(const float4*)(w + t * 4);
    float4 o;
    o.x = v.x * scale * w4.x;
    o.y = v.y * scale * w4.y;
    o.z = v.z * scale * w4.z;
    o.w = v.w * scale * w4.w;
    *(float4*)(out + (size_t)row * DMODEL + t * 4) = o;
}

// ---------------------------------------------------------------------------
// Tiled fp32 GEMM: C[m][n] (+)= act( sum_k A[m][k] * W[n][k] )
// A: (M,K) row-major, W: (N,K) row-major. 64x64 tile, 256 threads, 4x4/thread.
// ACT: 0=none, 1=silu. ACC: accumulate into C.
template <int ACT, bool ACC>
__global__ __launch_bounds__(256) void gemm_nt(const float* __restrict__ A,
                                               const float* __restrict__ W,
                                               float* __restrict__ C,
                                               int M, int N, int K) {
    __shared__ float As[16][68];
    __shared__ float Ws[16][68];
    const int tid = threadIdx.x;
    const int tx = tid & 15, ty = tid >> 4;
    const int m0 = blockIdx.y * 64, n0 = blockIdx.x * 64;
    const int lr = tid >> 2;         // 0..63 (row within tile)
    const int lk = (tid & 3) * 4;    // 0,4,8,12 (k offset)
    float acc[4][4] = {};
    const float* Ap = A + (size_t)(m0 + lr) * K + lk;
    const float* Wp = W + (size_t)(n0 + lr) * K + lk;
    for (int k0 = 0; k0 < K; k0 += 16) {
        float4 av = *(const float4*)(Ap + k0);
        float4 wv = *(const float4*)(Wp + k0);
        As[lk + 0][lr] = av.x; As[lk + 1][lr] = av.y;
        As[lk + 2][lr] = av.z; As[lk + 3][lr] = av.w;
        Ws[lk + 0][lr] = wv.x; Ws[lk + 1][lr] = wv.y;
        Ws[lk + 2][lr] = wv.z; Ws[lk + 3][lr] = wv.w;
        __syncthreads();
#pragma unroll
        for (int kk = 0; kk < 16; ++kk) {
            const float4 a4 = *(const float4*)&As[kk][ty * 4];
            const float4 b4 = *(const float4*)&Ws[kk][tx * 4];
            const float aa[4] = {a4.x, a4.y, a4.z, a4.w};
            const float bb[4] = {b4.x, b4.y, b4.z, b4.w};
#pragma unroll
            for (int i = 0; i < 4; ++i)
#pragma unroll
                for (int j = 0; j < 4; ++j)
                    acc[i][j] = fmaf(aa[i], bb[j], acc[i][j]);
        }
        __syncthreads();
    }
#pragma unroll
    for (int i = 0; i < 4; ++i) {
        const int row = m0 + ty * 4 + i;
#pragma unroll
        for (int j = 0; j < 4; ++j) {
            const int col = n0 + tx * 4 + j;
            float v = acc[i][j];
            if (ACT == 1) v = v / (1.0f + expf(-v));
            size_t idx = (size_t)row * N + col;
            if (ACC) C[idx] += v; else C[idx] = v;
        }
    }
}

// ---------------------------------------------------------------------------
// Post-QKV: per-head RMS norm (q,k) + RoPE (q,k) + layout transforms.
// q: (T, H*HD) -> qT (H, T, HD)
// k: (T, KV*HD) -> keys_out (KV, T, HD)   (normed + rope'd)
// v: (T, KV*HD) -> vals_out (KV, T, HD)   (plain transpose)
// One wave per row; 4 rows per 256-thr block. Rows enumerated t*32 + c,
// c<16: q head c; 16<=c<24: k head c-16; c>=24: v head c-24.
__global__ __launch_bounds__(256) void qkv_post_k(
    const float* __restrict__ qbuf, const float* __restrict__ kbuf,
    const float* __restrict__ vbuf, const float* __restrict__ qn,
    const float* __restrict__ kn, const float* __restrict__ cosT,
    const float* __restrict__ sinT, float* __restrict__ qT,
    float* __restrict__ kout, float* __restrict__ vout) {
    const int r = blockIdx.x * 4 + (threadIdx.x >> 6);
    const int lane = threadIdx.x & 63;
    const int t = r >> 5, c = r & 31;
    const float* src;
    float* dst;
    const float* nw = nullptr;
    if (c < 16) {
        src = qbuf + (size_t)t * (NH * HDIM) + c * HDIM;
        dst = qT + ((size_t)c * SEQ + t) * HDIM;
        nw = qn;
    } else if (c < 24) {
        int kh = c - 16;
        src = kbuf + (size_t)t * (NKV * HDIM) + kh * HDIM;
        dst = kout + ((size_t)kh * SEQ + t) * HDIM;
        nw = kn;
    } else {
        int vh = c - 24;
        src = vbuf + (size_t)t * (NKV * HDIM) + vh * HDIM;
        dst = vout + ((size_t)vh * SEQ + t) * HDIM;
    }
    float x1 = src[lane];
    float x2 = src[lane + 64];
    if (c >= 24) {  // v: plain copy/transpose
        dst[lane] = x1;
        dst[lane + 64] = x2;
        return;
    }
    float ss = x1 * x1 + x2 * x2;
#pragma unroll
    for (int off = 32; off >= 1; off >>= 1) ss += __shfl_xor(ss, off, 64);
    float scale = rsqrtf(ss * (1.0f / HDIM) + RMS_EPS);
    float xn1 = x1 * scale * nw[lane];
    float xn2 = x2 * scale * nw[lane + 64];
    float cc = cosT[t * 64 + lane];
    float sv = sinT[t * 64 + lane];
    dst[lane] = xn1 * cc - xn2 * sv;
    dst[lane + 64] = xn2 * cc + xn1 * sv;
}

// ---------------------------------------------------------------------------
// Flash attention (fp32), causal. Grid: (T/32, H). 256 threads.
// Q: (H, T, HD). K,V: (KV, T, HD). O: (T, H*HD).
__global__ __launch_bounds__(256) void attn_k(const float* __restrict__ Q,
                                              const float* __restrict__ Kc,
                                              const float* __restrict__ Vc,
                                              float* __restrict__ O) {
    __shared__ float q_s[32][132];
    __shared__ float k_s[32][132];
    __shared__ float v_s[32][132];
    __shared__ float s_s[32][36];
    const int tid = threadIdx.x;
    const int head = blockIdx.y;
    const int kvh = head >> 1;  // GQA=2
    const int qb0 = blockIdx.x * 32;
    const float* qp = Q + ((size_t)head * SEQ + qb0) * HDIM;
#pragma unroll
    for (int it = 0; it < 4; ++it) {
        int idx = tid + it * 256;      // float4 index within 32x128 tile
        int rr = idx >> 5;
        int c4 = (idx & 31) * 4;
        *(float4*)&q_s[rr][c4] = *(const float4*)(qp + idx * 4);
    }
    float m_r = -1e30f, l_r = 0.0f;
    float acc[16] = {};
    const int qrow = tid >> 3, sub = tid & 7;
    const int d0 = sub * 16;
    const int tx = tid & 15, ty = tid >> 4;
    const int nkb = blockIdx.x + 1;
    const float* kbase = Kc + (size_t)kvh * SEQ * HDIM;
    const float* vbase = Vc + (size_t)kvh * SEQ * HDIM;
    for (int kb = 0; kb < nkb; ++kb) {
        const int k0 = kb * 32;
        __syncthreads();  // previous iteration's PV reads done
#pragma unroll
        for (int it = 0; it < 4; ++it) {
            int idx = tid + it * 256;
            int rr = idx >> 5;
            int c4 = (idx & 31) * 4;
            *(float4*)&k_s[rr][c4] = *(const float4*)(kbase + (size_t)k0 * HDIM + idx * 4);
            *(float4*)&v_s[rr][c4] = *(const float4*)(vbase + (size_t)k0 * HDIM + idx * 4);
        }
        __syncthreads();
        // scores: 16x16 threads, 2x2 each
        float sc00 = 0.f, sc01 = 0.f, sc10 = 0.f, sc11 = 0.f;
#pragma unroll
        for (int h = 0; h < HDIM; h += 4) {
            const float4 qa = *(const float4*)&q_s[ty][h];
            const float4 qb = *(const float4*)&q_s[ty + 16][h];
            const float4 ka = *(const float4*)&k_s[tx][h];
            const float4 kb4 = *(const float4*)&k_s[tx + 16][h];
            sc00 = fmaf(qa.x, ka.x, fmaf(qa.y, ka.y, fmaf(qa.z, ka.z, fmaf(qa.w, ka.w, sc00))));
            sc01 = fmaf(qa.x, kb4.x, fmaf(qa.y, kb4.y, fmaf(qa.z, kb4.z, fmaf(qa.w, kb4.w, sc01))));
            sc10 = fmaf(qb.x, ka.x, fmaf(qb.y, ka.y, fmaf(qb.z, ka.z, fmaf(qb.w, ka.w, sc10))));
            sc11 = fmaf(qb.x, kb4.x, fmaf(qb.y, kb4.y, fmaf(qb.z, kb4.z, fmaf(qb.w, kb4.w, sc11))));
        }
        {
            const int qi0 = qb0 + ty, qi1 = qb0 + ty + 16;
            const int ki0 = k0 + tx, ki1 = k0 + tx + 16;
            s_s[ty][tx]           = (qi0 >= ki0) ? sc00 * ATT_SCALE : -1e30f;
            s_s[ty][tx + 16]      = (qi0 >= ki1) ? sc01 * ATT_SCALE : -1e30f;
            s_s[ty + 16][tx]      = (qi1 >= ki0) ? sc10 * ATT_SCALE : -1e30f;
            s_s[ty + 16][tx + 16] = (qi1 >= ki1) ? sc11 * ATT_SCALE : -1e30f;
        }
        __syncthreads();
        // online softmax: 8 threads per q-row
        float4 sv4 = *(const float4*)&s_s[qrow][sub * 4];
        float mloc = fmaxf(fmaxf(sv4.x, sv4.y), fmaxf(sv4.z, sv4.w));
#pragma unroll
        for (int off = 1; off < 8; off <<= 1) mloc = fmaxf(mloc, __shfl_xor(mloc, off, 8));
        const float m_new = fmaxf(m_r, mloc);
        const float alpha = expf(m_r - m_new);
        const float p0 = expf(sv4.x - m_new);
        const float p1 = expf(sv4.y - m_new);
        const float p2 = expf(sv4.z - m_new);
        const float p3 = expf(sv4.w - m_new);
        float lsum = p0 + p1 + p2 + p3;
#pragma unroll
        for (int off = 1; off < 8; off <<= 1) lsum += __shfl_xor(lsum, off, 8);
        l_r = l_r * alpha + lsum;
        m_r = m_new;
        s_s[qrow][sub * 4 + 0] = p0;
        s_s[qrow][sub * 4 + 1] = p1;
        s_s[qrow][sub * 4 + 2] = p2;
        s_s[qrow][sub * 4 + 3] = p3;
#pragma unroll
        for (int j = 0; j < 16; ++j) acc[j] *= alpha;
        __syncthreads();
        // PV: thread owns (qrow, d0..d0+15)
        for (int k = 0; k < 32; ++k) {
            const float p = s_s[qrow][k];
            const float* vr = &v_s[k][d0];
            const float4 v0 = *(const float4*)(vr);
            const float4 v1 = *(const float4*)(vr + 4);
            const float4 v2 = *(const float4*)(vr + 8);
            const float4 v3 = *(const float4*)(vr + 12);
            acc[0]  = fmaf(p, v0.x, acc[0]);  acc[1]  = fmaf(p, v0.y, acc[1]);
            acc[2]  = fmaf(p, v0.z, acc[2]);  acc[3]  = fmaf(p, v0.w, acc[3]);
            acc[4]  = fmaf(p, v1.x, acc[4]);  acc[5]  = fmaf(p, v1.y, acc[5]);
            acc[6]  = fmaf(p, v1.z, acc[6]);  acc[7]  = fmaf(p, v1.w, acc[7]);
            acc[8]  = fmaf(p, v2.x, acc[8]);  acc[9]  = fmaf(p, v2.y, acc[9]);
            acc[10] = fmaf(p, v2.z, acc[10]); acc[11] = fmaf(p, v2.w, acc[11]);
            acc[12] = fmaf(p, v3.x, acc[12]); acc[13] = fmaf(p, v3.y, acc[13]);
            acc[14] = fmaf(p, v3.z, acc[14]); acc[15] = fmaf(p, v3.w, acc[15]);
        }
    }
    const float inv = 1.0f / l_r;
    float* op = O + (size_t)(qb0 + qrow) * (NH * HDIM) + head * HDIM + d0;
    float4 o0 = {acc[0] * inv, acc[1] * inv, acc[2] * inv, acc[3] * inv};
    float4 o1 = {acc[4] * inv, acc[5] * inv, acc[6] * inv, acc[7] * inv};
    float4 o2 = {acc[8] * inv, acc[9] * inv, acc[10] * inv, acc[11] * inv};
    float4 o3 = {acc[12] * inv, acc[13] * inv, acc[14] * inv, acc[15] * inv};
    *(float4*)(op + 0) = o0;
    *(float4*)(op + 4) = o1;
    *(float4*)(op + 8) = o2;
    *(float4*)(op + 12) = o3;
}

// ---------------------------------------------------------------------------
// Elementwise: g *= u (grid-stride, float4)
__global__ __launch_bounds__(256) void mul_k(float* __restrict__ g,
                                             const float* __restrict__ u, int n4) {
    for (int i = blockIdx.x * blockDim.x + threadIdx.x; i < n4;
         i += gridDim.x * blockDim.x) {
        float4 a = ((const float4*)g)[i];
        float4 b = ((const float4*)u)[i];
        a.x *= b.x; a.y *= b.y; a.z *= b.z; a.w *= b.w;
        ((float4*)g)[i] = a;
    }
}

// ---------------------------------------------------------------------------
extern "C" void kernel_launch(void* const* d_in, const int* in_sizes, int n_in,
                              void* d_out, int out_size, void* d_ws, size_t ws_size,
                              hipStream_t stream) {
    const float* emb = (const float*)d_in[0];
    const float* ln1 = (const float*)d_in[1];
    const float* qw  = (const float*)d_in[2];
    const float* kw  = (const float*)d_in[3];
    const float* vw  = (const float*)d_in[4];
    const float* qn  = (const float*)d_in[5];
    const float* kn  = (const float*)d_in[6];
    const float* ow  = (const float*)d_in[7];
    const float* ln2 = (const float*)d_in[8];
    const float* gw  = (const float*)d_in[9];
    const float* uw  = (const float*)d_in[10];
    const float* dw  = (const float*)d_in[11];
    const float* nw  = (const float*)d_in[12];

    float* out  = (float*)d_out;
    float* keys = out + (size_t)SEQ * DMODEL;                       // (L,KV,T,HD)
    float* vals = keys + (size_t)LAYERS * NKV * SEQ * HDIM;

    float* ws = (float*)d_ws;
    float* h    = ws;                         // T*D
    float* x    = h + (size_t)SEQ * DMODEL;   // T*D
    float* qbuf = x + (size_t)SEQ * DMODEL;   // T*H*HD (reused as attn out)
    float* qT   = qbuf + (size_t)SEQ * NH * HDIM;    // H*T*HD
    float* kbuf = qT + (size_t)SEQ * NH * HDIM;      // T*KV*HD
    float* vbuf = kbuf + (size_t)SEQ * NKV * HDIM;   // T*KV*HD
    float* g    = vbuf + (size_t)SEQ * NKV * HDIM;   // T*FF
    float* u    = g + (size_t)SEQ * FFD;             // T*FF
    float* cosT = u + (size_t)SEQ * FFD;             // T*64
    float* sinT = cosT + (size_t)SEQ * 64;           // T*64

    hipMemcpyAsync(h, emb, sizeof(float) * SEQ * DMODEL,
                   hipMemcpyDeviceToDevice, stream);
    rope_init_k<<<SEQ, 64, 0, stream>>>(cosT, sinT);

    const dim3 blk(256);
    for (int i = 0; i < LAYERS; ++i) {
        const float* qwi = qw + (size_t)i * NH * HDIM * DMODEL;
        const float* kwi = kw + (size_t)i * NKV * HDIM * DMODEL;
        const float* vwi = vw + (size_t)i * NKV * HDIM * DMODEL;
        const float* owi = ow + (size_t)i * DMODEL * NH * HDIM;
        const float* gwi = gw + (size_t)i * FFD * DMODEL;
        const float* uwi = uw + (size_t)i * FFD * DMODEL;
        const float* dwi = dw + (size_t)i * DMODEL * FFD;
        float* keys_i = keys + (size_t)i * NKV * SEQ * HDIM;
        float* vals_i = vals + (size_t)i * NKV * SEQ * HDIM;

        // ln1
        rms_k<<<SEQ, blk, 0, stream>>>(h, ln1 + (size_t)i * DMODEL, x);
        // qkv projections
        gemm_nt<0, false><<<dim3((NH * HDIM) / 64, SEQ / 64), blk, 0, stream>>>(
            x, qwi, qbuf, SEQ, NH * HDIM, DMODEL);
        gemm_nt<0, false><<<dim3((NKV * HDIM) / 64, SEQ / 64), blk, 0, stream>>>(
            x, kwi, kbuf, SEQ, NKV * HDIM, DMODEL);
        gemm_nt<0, false><<<dim3((NKV * HDIM) / 64, SEQ / 64), blk, 0, stream>>>(
            x, vwi, vbuf, SEQ, NKV * HDIM, DMODEL);
        // qk norm + rope + transposes; writes keys/vals outputs directly
        qkv_post_k<<<SEQ * 32 / 4, blk, 0, stream>>>(
            qbuf, kbuf, vbuf, qn + (size_t)i * HDIM, kn + (size_t)i * HDIM,
            cosT, sinT, qT, keys_i, vals_i);
        // attention (reads keys/vals from d_out), writes attn out into qbuf
        attn_k<<<dim3(SEQ / 32, NH), blk, 0, stream>>>(qT, keys_i, vals_i, qbuf);
        // h += attn @ o_w^T
        gemm_nt<0, true><<<dim3(DMODEL / 64, SEQ / 64), blk, 0, stream>>>(
            qbuf, owi, h, SEQ, DMODEL, NH * HDIM);
        // ln2
        rms_k<<<SEQ, blk, 0, stream>>>(h, ln2 + (size_t)i * DMODEL, x);
        // mlp
        gemm_nt<1, false><<<dim3(FFD / 64, SEQ / 64), blk, 0, stream>>>(
            x, gwi, g, SEQ, FFD, DMODEL);
        gemm_nt<0, false><<<dim3(FFD / 64, SEQ / 64), blk, 0, stream>>>(
            x, uwi, u, SEQ, FFD, DMODEL);
        mul_k<<<2048, blk, 0, stream>>>(g, u, SEQ * FFD / 4);
        gemm_nt<0, true><<<dim3(DMODEL / 64, SEQ / 64), blk, 0, stream>>>(
            g, dwi, h, SEQ, DMODEL, FFD);
    }
    // final norm -> hs
    rms_k<<<SEQ, blk, 0, stream>>>(h, nw, out);
}

// Round 2
// 3165.115 us; speedup vs baseline: 3.1258x; 3.1258x over previous
//
#include <hip/hip_runtime.h>
#include <hip/hip_bf16.h>
#include <math.h>

#define LAYERS 5
#define DMODEL 1024
#define NH 16
#define NKV 8
#define HDIM 128
#define FFD 3072
#define SEQ 2048
#define RMS_EPS 1e-6f
// ATT_SCALE * log2(e):  0.08838834764831845 * 1.4426950408889634
#define SC2 0.12753292444440332f
#define NEGINF (-1e30f)

typedef __attribute__((ext_vector_type(8))) short bf16x8;
typedef __attribute__((ext_vector_type(4))) float f32x4;
typedef __attribute__((ext_vector_type(4))) unsigned short u16x4;

__device__ __forceinline__ unsigned short f2bf(float x) {
    unsigned int u = __float_as_uint(x);
    u = (u + 0x7fffu + ((u >> 16) & 1u)) >> 16;
    return (unsigned short)u;
}
__device__ __forceinline__ float bf2f(unsigned short b) {
    return __uint_as_float(((unsigned int)b) << 16);
}
__device__ __forceinline__ void fsplit(float x, unsigned short &h, unsigned short &l) {
    h = f2bf(x);
    l = f2bf(x - bf2f(h));
}

// ---------------------------------------------------------------------------
// RoPE tables (T x 64)
__global__ void rope_init_k(float* __restrict__ cosT, float* __restrict__ sinT) {
    int t = blockIdx.x;
    int j = threadIdx.x;  // 0..63
    double inv = pow(1.0e6, -((double)j) / 64.0);
    float angf = (float)t * (float)inv;
    double ang = (double)angf;
    cosT[t * 64 + j] = (float)cos(ang);
    sinT[t * 64 + j] = (float)sin(ang);
}

// ---------------------------------------------------------------------------
// RMSNorm over D=1024. SPLIT: write bf16 hi/lo pair; else fp32.
template <bool SPLIT>
__global__ __launch_bounds__(256) void rms_k(const float* __restrict__ in,
                                             const float* __restrict__ w,
                                             float* __restrict__ outf,
                                             unsigned short* __restrict__ oh,
                                             unsigned short* __restrict__ ol) {
    __shared__ float red[4];
    const int row = blockIdx.x;
    const int t = threadIdx.x;
    const float* p = in + (size_t)row * DMODEL;
    float4 v = *(const float4*)(p + t * 4);
    float ss = v.x * v.x + v.y * v.y + v.z * v.z + v.w * v.w;
#pragma unroll
    for (int off = 32; off >= 1; off >>= 1) ss += __shfl_xor(ss, off);
    if ((t & 63) == 0) red[t >> 6] = ss;
    __syncthreads();
    float tot = red[0] + red[1] + red[2] + red[3];
    float scale = rsqrtf(tot * (1.0f / DMODEL) + RMS_EPS);
    float4 w4 = *(const float4*)(w + t * 4);
    float o0 = v.x * scale * w4.x;
    float o1 = v.y * scale * w4.y;
    float o2 = v.z * scale * w4.z;
    float o3 = v.w * scale * w4.w;
    if (SPLIT) {
        unsigned short h0, h1, h2, h3, l0, l1, l2, l3;
        fsplit(o0, h0, l0); fsplit(o1, h1, l1); fsplit(o2, h2, l2); fsplit(o3, h3, l3);
        u16x4 hh = {h0, h1, h2, h3};
        u16x4 ll = {l0, l1, l2, l3};
        *(u16x4*)(oh + (size_t)row * DMODEL + t * 4) = hh;
        *(u16x4*)(ol + (size_t)row * DMODEL + t * 4) = ll;
    } else {
        float4 o = {o0, o1, o2, o3};
        *(float4*)(outf + (size_t)row * DMODEL + t * 4) = o;
    }
}

// ---------------------------------------------------------------------------
// fp32 -> bf16 hi/lo split (weights), float4 granularity
__global__ __launch_bounds__(256) void convert_w_k(const float* __restrict__ src,
                                                   unsigned short* __restrict__ hi,
                                                   unsigned short* __restrict__ lo,
                                                   int n4) {
    int i = blockIdx.x * 256 + threadIdx.x;
    if (i >= n4) return;
    float4 v = ((const float4*)src)[i];
    unsigned short h0, h1, h2, h3, l0, l1, l2, l3;
    fsplit(v.x, h0, l0); fsplit(v.y, h1, l1); fsplit(v.z, h2, l2); fsplit(v.w, h3, l3);
    u16x4 hh = {h0, h1, h2, h3};
    u16x4 ll = {l0, l1, l2, l3};
    ((u16x4*)hi)[i] = hh;
    ((u16x4*)lo)[i] = ll;
}

// ---------------------------------------------------------------------------
// Split-precision bf16 MFMA GEMM:  C[m][n] (+)= act( sum_k A[m][k]*B[n][k] )
// A,B pre-split bf16 (hi/lo) row-major with leading dim K. 128x128 tile, BK=32,
// 4 waves (64x64 per wave, 4x4 frags of 16x16x32). acc = Al*Bh + Ah*Bl + Ah*Bh.
// Fragment-contiguous LDS: unit (c=k/8, r=row) -> byte (c*128+r)*16: conflict-free.
template <bool ACC>
__global__ __launch_bounds__(256, 2) void gemm_sp(
    const unsigned short* __restrict__ Ah, const unsigned short* __restrict__ Al,
    const unsigned short* __restrict__ Bh, const unsigned short* __restrict__ Bl,
    float* __restrict__ C, int N, int K, int actsplit) {
    __shared__ __align__(16) char lds[32768];  // Ah|Al|Bh|Bl 8KB each
    const int tid = threadIdx.x;
    const int m0 = blockIdx.y * 128, n0 = blockIdx.x * 128;
    const int lane = tid & 63, wave = tid >> 6;
    const int wm = wave >> 1, wn = wave & 1;
    const int lr = lane & 15, lg = lane >> 4;
    const int c_ = tid & 3, r_ = tid >> 2;  // staging unit (c_, r_) and (c_, r_+64)

    f32x4 zero = {0.f, 0.f, 0.f, 0.f};
    f32x4 acc[4][4];
#pragma unroll
    for (int m = 0; m < 4; ++m)
#pragma unroll
        for (int n = 0; n < 4; ++n) acc[m][n] = zero;

    const size_t arow0 = (size_t)(m0 + r_) * K;
    const size_t arow1 = (size_t)(m0 + r_ + 64) * K;
    const size_t brow0 = (size_t)(n0 + r_) * K;
    const size_t brow1 = (size_t)(n0 + r_ + 64) * K;
    const int koff = c_ * 8;

    for (int k0 = 0; k0 < K; k0 += 32) {
        bf16x8 a0 = *(const bf16x8*)(Ah + arow0 + k0 + koff);
        bf16x8 a1 = *(const bf16x8*)(Ah + arow1 + k0 + koff);
        bf16x8 a2 = *(const bf16x8*)(Al + arow0 + k0 + koff);
        bf16x8 a3 = *(const bf16x8*)(Al + arow1 + k0 + koff);
        bf16x8 b0 = *(const bf16x8*)(Bh + brow0 + k0 + koff);
        bf16x8 b1 = *(const bf16x8*)(Bh + brow1 + k0 + koff);
        bf16x8 b2 = *(const bf16x8*)(Bl + brow0 + k0 + koff);
        bf16x8 b3 = *(const bf16x8*)(Bl + brow1 + k0 + koff);
        *(bf16x8*)(lds + (c_ * 128 + r_) * 16) = a0;
        *(bf16x8*)(lds + (c_ * 128 + r_ + 64) * 16) = a1;
        *(bf16x8*)(lds + 8192 + (c_ * 128 + r_) * 16) = a2;
        *(bf16x8*)(lds + 8192 + (c_ * 128 + r_ + 64) * 16) = a3;
        *(bf16x8*)(lds + 16384 + (c_ * 128 + r_) * 16) = b0;
        *(bf16x8*)(lds + 16384 + (c_ * 128 + r_ + 64) * 16) = b1;
        *(bf16x8*)(lds + 24576 + (c_ * 128 + r_) * 16) = b2;
        *(bf16x8*)(lds + 24576 + (c_ * 128 + r_ + 64) * 16) = b3;
        __syncthreads();
        bf16x8 fAh[4], fAl[4], fBh[4], fBl[4];
#pragma unroll
        for (int m = 0; m < 4; ++m) {
            int u = lg * 128 + wm * 64 + m * 16 + lr;
            fAh[m] = *(const bf16x8*)(lds + u * 16);
            fAl[m] = *(const bf16x8*)(lds + 8192 + u * 16);
        }
#pragma unroll
        for (int n = 0; n < 4; ++n) {
            int u = lg * 128 + wn * 64 + n * 16 + lr;
            fBh[n] = *(const bf16x8*)(lds + 16384 + u * 16);
            fBl[n] = *(const bf16x8*)(lds + 24576 + u * 16);
        }
#pragma unroll
        for (int m = 0; m < 4; ++m)
#pragma unroll
            for (int n = 0; n < 4; ++n) {
                acc[m][n] = __builtin_amdgcn_mfma_f32_16x16x32_bf16(fAl[m], fBh[n], acc[m][n], 0, 0, 0);
                acc[m][n] = __builtin_amdgcn_mfma_f32_16x16x32_bf16(fAh[m], fBl[n], acc[m][n], 0, 0, 0);
                acc[m][n] = __builtin_amdgcn_mfma_f32_16x16x32_bf16(fAh[m], fBh[n], acc[m][n], 0, 0, 0);
            }
        __syncthreads();
    }
#pragma unroll
    for (int m = 0; m < 4; ++m) {
        const int row = m0 + wm * 64 + m * 16 + lg * 4;
#pragma unroll
        for (int n = 0; n < 4; ++n) {
            const int col = n0 + wn * 64 + n * 16 + lr;
            const bool act = col < actsplit;
            float* cp = C + (size_t)row * N + col;
#pragma unroll
            for (int j = 0; j < 4; ++j) {
                float v = acc[m][n][j];
                if (act) v = v / (1.0f + expf(-v));
                if (ACC) cp[(size_t)j * N] += v;
                else cp[(size_t)j * N] = v;
            }
        }
    }
}

// ---------------------------------------------------------------------------
// Post-QKV: qk-norm + rope; q -> bf16 [H][T][HD]; k -> keys fp32 + bf16 copy;
// v -> vals fp32. kvbuf is [T][2048]: k cols 0..1023, v cols 1024..2047.
__global__ __launch_bounds__(256) void qkv_post_k(
    const float* __restrict__ qbuf, const float* __restrict__ kvbuf,
    const float* __restrict__ qn, const float* __restrict__ kn,
    const float* __restrict__ cosT, const float* __restrict__ sinT,
    unsigned short* __restrict__ qb16, float* __restrict__ keys,
    unsigned short* __restrict__ kb16, float* __restrict__ vals) {
    const int r = blockIdx.x * 4 + (threadIdx.x >> 6);
    const int lane = threadIdx.x & 63;
    const int t = r >> 5, c = r & 31;
    if (c >= 24) {  // v: copy/transpose
        const int vh = c - 24;
        const float* src = kvbuf + (size_t)t * 2048 + 1024 + vh * 128;
        float* dst = vals + ((size_t)vh * SEQ + t) * 128;
        dst[lane] = src[lane];
        dst[lane + 64] = src[lane + 64];
        return;
    }
    const float* src;
    const float* nw;
    if (c < 16) { src = qbuf + (size_t)t * 2048 + c * 128; nw = qn; }
    else        { src = kvbuf + (size_t)t * 2048 + (c - 16) * 128; nw = kn; }
    float x1 = src[lane], x2 = src[lane + 64];
    float ss = x1 * x1 + x2 * x2;
#pragma unroll
    for (int off = 32; off >= 1; off >>= 1) ss += __shfl_xor(ss, off);
    float scale = rsqrtf(ss * (1.0f / HDIM) + RMS_EPS);
    float xn1 = x1 * scale * nw[lane];
    float xn2 = x2 * scale * nw[lane + 64];
    float cc = cosT[t * 64 + lane], sv = sinT[t * 64 + lane];
    float o1 = xn1 * cc - xn2 * sv;
    float o2 = xn2 * cc + xn1 * sv;
    if (c < 16) {
        unsigned short* dst = qb16 + ((size_t)c * SEQ + t) * 128;
        dst[lane] = f2bf(o1);
        dst[lane + 64] = f2bf(o2);
    } else {
        const int kh = c - 16;
        float* kd = keys + ((size_t)kh * SEQ + t) * 128;
        kd[lane] = o1;
        kd[lane + 64] = o2;
        unsigned short* kb = kb16 + ((size_t)kh * SEQ + t) * 128;
        kb[lane] = f2bf(o1);
        kb[lane + 64] = f2bf(o2);
    }
}

// ---------------------------------------------------------------------------
// V transpose: vals fp32 [KV][T][HD] -> vt bf16 [KV][HD][T]
__global__ __launch_bounds__(256) void vtrans_k(const float* __restrict__ vals,
                                                unsigned short* __restrict__ vt) {
    __shared__ float tile[32][33];
    const int t0 = blockIdx.x * 32, d0 = blockIdx.y * 32, kvh = blockIdx.z;
    const int a = threadIdx.x >> 3, b4 = (threadIdx.x & 7) * 4;
    const float4 v = *(const float4*)(vals + ((size_t)kvh * SEQ + t0 + a) * 128 + d0 + b4);
    tile[a][b4] = v.x; tile[a][b4 + 1] = v.y; tile[a][b4 + 2] = v.z; tile[a][b4 + 3] = v.w;
    __syncthreads();
    u16x4 o = {f2bf(tile[b4][a]), f2bf(tile[b4 + 1][a]), f2bf(tile[b4 + 2][a]), f2bf(tile[b4 + 3][a])};
    *(u16x4*)(vt + ((size_t)kvh * HDIM + d0 + a) * SEQ + t0 + b4) = o;
}

// ---------------------------------------------------------------------------
// Flash attention, bf16 MFMA, causal. Block: 4 waves, 128 q-rows (32/wave).
// S^T = mfma(K, Q): softmax over k is in-lane (8 vals) + 2 shuffles.
// P^T -> LDS (bf16, XOR-swizzled) -> O^T = mfma(V^T, P).
// Grid: (T/128, H).
__global__ __launch_bounds__(256, 2) void attn_k(
    const unsigned short* __restrict__ Qb, const unsigned short* __restrict__ Kb,
    const unsigned short* __restrict__ Vt,
    unsigned short* __restrict__ AOh, unsigned short* __restrict__ AOl) {
    __shared__ __align__(16) char lds[24576];  // K 8KB | Vt 8KB | P 4x2KB
    const int tid = threadIdx.x;
    const int wave = tid >> 6, lane = tid & 63;
    const int lr = lane & 15, lg = lane >> 4;
    const int head = blockIdx.y, kvh = head >> 1;
    const int qb = blockIdx.x * 128;
    const int qw = qb + wave * 32;
    char* Klds = lds;
    char* Vlds = lds + 8192;
    char* Plds = lds + 16384 + wave * 2048;

    bf16x8 qf[2][4];
#pragma unroll
    for (int qg = 0; qg < 2; ++qg)
#pragma unroll
        for (int ds = 0; ds < 4; ++ds)
            qf[qg][ds] = *(const bf16x8*)(Qb + ((size_t)head * SEQ + qw + qg * 16 + lr) * 128 + ds * 32 + lg * 8);

    f32x4 zero = {0.f, 0.f, 0.f, 0.f};
    f32x4 oacc[2][8];
#pragma unroll
    for (int qg = 0; qg < 2; ++qg)
#pragma unroll
        for (int dg = 0; dg < 8; ++dg) oacc[qg][dg] = zero;
    float m_r[2] = {NEGINF, NEGINF};
    float l_r[2] = {0.f, 0.f};

    const int s_k0 = tid >> 4, s_db = tid & 15;  // K staging: (k, dblk)
    const int s_d0 = tid >> 2, s_kb = tid & 3;   // V staging: (d, kblk)

    const int nkv = (qb >> 5) + 4;
    for (int kv = 0; kv < nkv; ++kv) {
        const int k0 = kv * 32;
        __syncthreads();
        {
            bf16x8 t0 = *(const bf16x8*)(Kb + ((size_t)kvh * SEQ + k0 + s_k0) * 128 + s_db * 8);
            bf16x8 t1 = *(const bf16x8*)(Kb + ((size_t)kvh * SEQ + k0 + s_k0 + 16) * 128 + s_db * 8);
            *(bf16x8*)(Klds + ((s_k0 * 256 + s_db * 16) ^ ((s_k0 & 7) << 4))) = t0;
            *(bf16x8*)(Klds + (((s_k0 + 16) * 256 + s_db * 16) ^ (((s_k0 + 16) & 7) << 4))) = t1;
            bf16x8 v0 = *(const bf16x8*)(Vt + ((size_t)kvh * HDIM + s_d0) * SEQ + k0 + s_kb * 8);
            bf16x8 v1 = *(const bf16x8*)(Vt + ((size_t)kvh * HDIM + s_d0 + 64) * SEQ + k0 + s_kb * 8);
            *(bf16x8*)(Vlds + ((s_d0 * 64 + s_kb * 16) ^ ((s_d0 & 7) << 4))) = v0;
            *(bf16x8*)(Vlds + (((s_d0 + 64) * 64 + s_kb * 16) ^ (((s_d0 + 64) & 7) << 4))) = v1;
        }
        __syncthreads();
        // S^T[k][q]
        f32x4 S[2][2];
        S[0][0] = zero; S[0][1] = zero; S[1][0] = zero; S[1][1] = zero;
#pragma unroll
        for (int ds = 0; ds < 4; ++ds) {
#pragma unroll
            for (int kg = 0; kg < 2; ++kg) {
                const int krow = kg * 16 + lr;
                bf16x8 kf = *(const bf16x8*)(Klds + ((krow * 256 + ds * 64 + lg * 16) ^ ((krow & 7) << 4)));
                S[kg][0] = __builtin_amdgcn_mfma_f32_16x16x32_bf16(kf, qf[0][ds], S[kg][0], 0, 0, 0);
                S[kg][1] = __builtin_amdgcn_mfma_f32_16x16x32_bf16(kf, qf[1][ds], S[kg][1], 0, 0, 0);
            }
        }
        // online softmax per q-column (q = qw + qg*16 + lr)
#pragma unroll
        for (int qg = 0; qg < 2; ++qg) {
            const int q = qw + qg * 16 + lr;
            float p[2][4];
            float mm = NEGINF;
#pragma unroll
            for (int kg = 0; kg < 2; ++kg)
#pragma unroll
                for (int j = 0; j < 4; ++j) {
                    const int kk = k0 + kg * 16 + lg * 4 + j;
                    float s = S[kg][qg][j] * SC2;
                    s = (kk <= q) ? s : NEGINF;
                    p[kg][j] = s;
                    mm = fmaxf(mm, s);
                }
            mm = fmaxf(mm, __shfl_xor(mm, 16));
            mm = fmaxf(mm, __shfl_xor(mm, 32));
            const float mnew = fmaxf(m_r[qg], mm);
            const float alpha = exp2f(m_r[qg] - mnew);
            m_r[qg] = mnew;
            float ps = 0.f;
#pragma unroll
            for (int kg = 0; kg < 2; ++kg)
#pragma unroll
                for (int j = 0; j < 4; ++j) {
                    float e = exp2f(p[kg][j] - mnew);
                    p[kg][j] = e;
                    ps += e;
                }
            ps += __shfl_xor(ps, 16);
            ps += __shfl_xor(ps, 32);
            l_r[qg] = l_r[qg] * alpha + ps;
#pragma unroll
            for (int dg = 0; dg < 8; ++dg) oacc[qg][dg] *= alpha;
            const int qloc = qg * 16 + lr;
#pragma unroll
            for (int kg = 0; kg < 2; ++kg)
#pragma unroll
                for (int j = 0; j < 4; ++j) {
                    const int kloc = kg * 16 + lg * 4 + j;
                    *(unsigned short*)(Plds + ((qloc * 64 + kloc * 2) ^ ((qloc & 7) << 4))) = f2bf(p[kg][j]);
                }
        }
        // PV: O^T[d][q] += V^T * P
        bf16x8 pf[2];
#pragma unroll
        for (int qg = 0; qg < 2; ++qg) {
            const int qloc = qg * 16 + lr;
            pf[qg] = *(const bf16x8*)(Plds + ((qloc * 64 + lg * 16) ^ ((qloc & 7) << 4)));
        }
#pragma unroll
        for (int dg = 0; dg < 8; ++dg) {
            const int drow = dg * 16 + lr;
            bf16x8 vf = *(const bf16x8*)(Vlds + ((drow * 64 + lg * 16) ^ ((drow & 7) << 4)));
            oacc[0][dg] = __builtin_amdgcn_mfma_f32_16x16x32_bf16(vf, pf[0], oacc[0][dg], 0, 0, 0);
            oacc[1][dg] = __builtin_amdgcn_mfma_f32_16x16x32_bf16(vf, pf[1], oacc[1][dg], 0, 0, 0);
        }
    }
    const float inv0 = 1.0f / l_r[0];
    const float inv1 = 1.0f / l_r[1];
#pragma unroll
    for (int qg = 0; qg < 2; ++qg) {
        const float iv = qg ? inv1 : inv0;
        const int t = qw + qg * 16 + lr;
#pragma unroll
        for (int dg = 0; dg < 8; ++dg) {
            const int col = head * 128 + dg * 16 + lg * 4;
            float v0 = oacc[qg][dg][0] * iv, v1 = oacc[qg][dg][1] * iv;
            float v2 = oacc[qg][dg][2] * iv, v3 = oacc[qg][dg][3] * iv;
            unsigned short h0, h1, h2, h3, l0, l1, l2, l3;
            fsplit(v0, h0, l0); fsplit(v1, h1, l1); fsplit(v2, h2, l2); fsplit(v3, h3, l3);
            u16x4 hh = {h0, h1, h2, h3};
            u16x4 ll = {l0, l1, l2, l3};
            *(u16x4*)(AOh + (size_t)t * 2048 + col) = hh;
            *(u16x4*)(AOl + (size_t)t * 2048 + col) = ll;
        }
    }
}

// ---------------------------------------------------------------------------
// gated product: p = g * u (g pre-silu'd by GEMM epilogue), split output
__global__ __launch_bounds__(256) void mulsplit_k(const float* __restrict__ gu,
                                                  unsigned short* __restrict__ ph,
                                                  unsigned short* __restrict__ pl) {
    const int c4 = blockIdx.x * 256 + threadIdx.x;  // 0..767
    const int row = blockIdx.y;
    const float* base = gu + (size_t)row * 6144;
    float4 g = *(const float4*)(base + c4 * 4);
    float4 u = *(const float4*)(base + 3072 + c4 * 4);
    float p0 = g.x * u.x, p1 = g.y * u.y, p2 = g.z * u.z, p3 = g.w * u.w;
    unsigned short h0, h1, h2, h3, l0, l1, l2, l3;
    fsplit(p0, h0, l0); fsplit(p1, h1, l1); fsplit(p2, h2, l2); fsplit(p3, h3, l3);
    u16x4 hh = {h0, h1, h2, h3};
    u16x4 ll = {l0, l1, l2, l3};
    *(u16x4*)(ph + (size_t)row * 3072 + c4 * 4) = hh;
    *(u16x4*)(pl + (size_t)row * 3072 + c4 * 4) = ll;
}

// ---------------------------------------------------------------------------
extern "C" void kernel_launch(void* const* d_in, const int* in_sizes, int n_in,
                              void* d_out, int out_size, void* d_ws, size_t ws_size,
                              hipStream_t stream) {
    const float* emb = (const float*)d_in[0];
    const float* ln1 = (const float*)d_in[1];
    const float* qw  = (const float*)d_in[2];
    const float* kw  = (const float*)d_in[3];
    const float* vw  = (const float*)d_in[4];
    const float* qn  = (const float*)d_in[5];
    const float* kn  = (const float*)d_in[6];
    const float* ow  = (const float*)d_in[7];
    const float* ln2 = (const float*)d_in[8];
    const float* gw  = (const float*)d_in[9];
    const float* uw  = (const float*)d_in[10];
    const float* dw  = (const float*)d_in[11];
    const float* nw  = (const float*)d_in[12];

    float* out  = (float*)d_out;
    float* keys = out + (size_t)SEQ * DMODEL;
    float* vals = keys + (size_t)LAYERS * NKV * SEQ * HDIM;

    // ws layout (total 113 MiB; gu aliases 16..64 MiB, ph/pl alias 64..88 MiB)
    char* W = (char*)d_ws;
    float* h             = (float*)(W);
    unsigned short* xh   = (unsigned short*)(W + (8ull << 20));
    unsigned short* xl   = (unsigned short*)(W + (12ull << 20));
    float* qbuf          = (float*)(W + (16ull << 20));
    float* kvbuf         = (float*)(W + (32ull << 20));
    unsigned short* qb16 = (unsigned short*)(W + (48ull << 20));
    unsigned short* kb16 = (unsigned short*)(W + (56ull << 20));
    unsigned short* vt16 = (unsigned short*)(W + (60ull << 20));
    unsigned short* aoh  = (unsigned short*)(W + (64ull << 20));
    unsigned short* aol  = (unsigned short*)(W + (72ull << 20));
    float* gu            = (float*)(W + (16ull << 20));           // alias
    unsigned short* ph   = (unsigned short*)(W + (64ull << 20));  // alias
    unsigned short* pl   = (unsigned short*)(W + (76ull << 20));  // alias
    unsigned short* wh   = (unsigned short*)(W + (88ull << 20));
    unsigned short* wl   = (unsigned short*)(W + (100ull << 20));
    float* cosT          = (float*)(W + (112ull << 20));
    float* sinT          = cosT + SEQ * 64;

    hipMemcpyAsync(h, emb, sizeof(float) * SEQ * DMODEL, hipMemcpyDeviceToDevice, stream);
    rope_init_k<<<SEQ, 64, 0, stream>>>(cosT, sinT);

    for (int i = 0; i < LAYERS; ++i) {
        float* keys_i = keys + (size_t)i * NKV * SEQ * HDIM;
        float* vals_i = vals + (size_t)i * NKV * SEQ * HDIM;
        // ln1 -> x (split)
        rms_k<true><<<SEQ, 256, 0, stream>>>(h, ln1 + (size_t)i * DMODEL, nullptr, xh, xl);
        // q proj
        convert_w_k<<<2048, 256, 0, stream>>>(qw + (size_t)i * 2097152, wh, wl, 524288);
        gemm_sp<false><<<dim3(16, 16), 256, 0, stream>>>(xh, xl, wh, wl, qbuf, 2048, 1024, 0);
        // k,v proj fused (B rows 0..1023 = k_w, 1024..2047 = v_w)
        convert_w_k<<<1024, 256, 0, stream>>>(kw + (size_t)i * 1048576, wh, wl, 262144);
        convert_w_k<<<1024, 256, 0, stream>>>(vw + (size_t)i * 1048576, wh + 1048576, wl + 1048576, 262144);
        gemm_sp<false><<<dim3(16, 16), 256, 0, stream>>>(xh, xl, wh, wl, kvbuf, 2048, 1024, 0);
        // qk-norm + rope + layout
        qkv_post_k<<<SEQ * 32 / 4, 256, 0, stream>>>(qbuf, kvbuf, qn + (size_t)i * HDIM,
                                                     kn + (size_t)i * HDIM, cosT, sinT,
                                                     qb16, keys_i, kb16, vals_i);
        vtrans_k<<<dim3(SEQ / 32, HDIM / 32, NKV), 256, 0, stream>>>(vals_i, vt16);
        attn_k<<<dim3(SEQ / 128, NH), 256, 0, stream>>>(qb16, kb16, vt16, aoh, aol);
        // o proj (accumulate into h)
        convert_w_k<<<2048, 256, 0, stream>>>(ow + (size_t)i * 2097152, wh, wl, 524288);
        gemm_sp<true><<<dim3(8, 16), 256, 0, stream>>>(aoh, aol, wh, wl, h, 1024, 2048, 0);
        // ln2 -> x (split)
        rms_k<true><<<SEQ, 256, 0, stream>>>(h, ln2 + (size_t)i * DMODEL, nullptr, xh, xl);
        // gate+up fused (rows 0..3071 = gate w/ silu, 3072..6143 = up)
        convert_w_k<<<3072, 256, 0, stream>>>(gw + (size_t)i * 3145728, wh, wl, 786432);
        convert_w_k<<<3072, 256, 0, stream>>>(uw + (size_t)i * 3145728, wh + 3145728, wl + 3145728, 786432);
        gemm_sp<false><<<dim3(48, 16), 256, 0, stream>>>(xh, xl, wh, wl, gu, 6144, 1024, 3072);
        mulsplit_k<<<dim3(3, SEQ), 256, 0, stream>>>(gu, ph, pl);
        // down proj (accumulate into h)
        convert_w_k<<<3072, 256, 0, stream>>>(dw + (size_t)i * 3145728, wh, wl, 786432);
        gemm_sp<true><<<dim3(8, 16), 256, 0, stream>>>(ph, pl, wh, wl, h, 1024, 3072, 0);
    }
    // final norm -> hs
    rms_k<false><<<SEQ, 256, 0, stream>>>(h, nw, out, nullptr, nullptr);
}

// Round 3
// 2892.701 us; speedup vs baseline: 3.4202x; 1.0942x over previous
//
#include <hip/hip_runtime.h>
#include <hip/hip_bf16.h>
#include <math.h>

#define LAYERS 5
#define DMODEL 1024
#define NH 16
#define NKV 8
#define HDIM 128
#define FFD 3072
#define SEQ 2048
#define RMS_EPS 1e-6f
// ATT_SCALE * log2(e):  0.08838834764831845 * 1.4426950408889634
#define SC2 0.12753292444440332f
#define NEGINF (-1e30f)

typedef __attribute__((ext_vector_type(8))) short bf16x8;
typedef __attribute__((ext_vector_type(4))) float f32x4;
typedef __attribute__((ext_vector_type(4))) unsigned short u16x4;

__device__ __forceinline__ unsigned short f2bf(float x) {
    unsigned int u = __float_as_uint(x);
    u = (u + 0x7fffu + ((u >> 16) & 1u)) >> 16;
    return (unsigned short)u;
}
__device__ __forceinline__ float bf2f(unsigned short b) {
    return __uint_as_float(((unsigned int)b) << 16);
}
__device__ __forceinline__ void fsplit(float x, unsigned short &h, unsigned short &l) {
    h = f2bf(x);
    l = f2bf(x - bf2f(h));
}

// ---------------------------------------------------------------------------
// RoPE tables (T x 64)
__global__ void rope_init_k(float* __restrict__ cosT, float* __restrict__ sinT) {
    int t = blockIdx.x;
    int j = threadIdx.x;  // 0..63
    double inv = pow(1.0e6, -((double)j) / 64.0);
    float angf = (float)t * (float)inv;
    double ang = (double)angf;
    cosT[t * 64 + j] = (float)cos(ang);
    sinT[t * 64 + j] = (float)sin(ang);
}

// ---------------------------------------------------------------------------
// RMSNorm over D=1024. SPLIT: write bf16 hi/lo pair; else fp32.
template <bool SPLIT>
__global__ __launch_bounds__(256) void rms_k(const float* __restrict__ in,
                                             const float* __restrict__ w,
                                             float* __restrict__ outf,
                                             unsigned short* __restrict__ oh,
                                             unsigned short* __restrict__ ol) {
    __shared__ float red[4];
    const int row = blockIdx.x;
    const int t = threadIdx.x;
    const float* p = in + (size_t)row * DMODEL;
    float4 v = *(const float4*)(p + t * 4);
    float ss = v.x * v.x + v.y * v.y + v.z * v.z + v.w * v.w;
#pragma unroll
    for (int off = 32; off >= 1; off >>= 1) ss += __shfl_xor(ss, off);
    if ((t & 63) == 0) red[t >> 6] = ss;
    __syncthreads();
    float tot = red[0] + red[1] + red[2] + red[3];
    float scale = rsqrtf(tot * (1.0f / DMODEL) + RMS_EPS);
    float4 w4 = *(const float4*)(w + t * 4);
    float o0 = v.x * scale * w4.x;
    float o1 = v.y * scale * w4.y;
    float o2 = v.z * scale * w4.z;
    float o3 = v.w * scale * w4.w;
    if (SPLIT) {
        unsigned short h0, h1, h2, h3, l0, l1, l2, l3;
        fsplit(o0, h0, l0); fsplit(o1, h1, l1); fsplit(o2, h2, l2); fsplit(o3, h3, l3);
        u16x4 hh = {h0, h1, h2, h3};
        u16x4 ll = {l0, l1, l2, l3};
        *(u16x4*)(oh + (size_t)row * DMODEL + t * 4) = hh;
        *(u16x4*)(ol + (size_t)row * DMODEL + t * 4) = ll;
    } else {
        float4 o = {o0, o1, o2, o3};
        *(float4*)(outf + (size_t)row * DMODEL + t * 4) = o;
    }
}

// ---------------------------------------------------------------------------
// fp32 -> bf16 hi/lo split (weights), float4 granularity
__global__ __launch_bounds__(256) void convert_w_k(const float* __restrict__ src,
                                                   unsigned short* __restrict__ hi,
                                                   unsigned short* __restrict__ lo,
                                                   int n4) {
    int i = blockIdx.x * 256 + threadIdx.x;
    if (i >= n4) return;
    float4 v = ((const float4*)src)[i];
    unsigned short h0, h1, h2, h3, l0, l1, l2, l3;
    fsplit(v.x, h0, l0); fsplit(v.y, h1, l1); fsplit(v.z, h2, l2); fsplit(v.w, h3, l3);
    u16x4 hh = {h0, h1, h2, h3};
    u16x4 ll = {l0, l1, l2, l3};
    ((u16x4*)hi)[i] = hh;
    ((u16x4*)lo)[i] = ll;
}

// ---------------------------------------------------------------------------
// Split-precision bf16 MFMA GEMM:  C[m][n] (+)= act( sum_k A[m][k]*B[n][k] )
// A,B pre-split bf16 (hi/lo) row-major, leading dim K. Tile BM x 128, BK=32,
// 4 waves. acc = Al*Bh + Ah*Bl + Ah*Bh (fp32-grade accuracy).
// Staging: global_load_lds width=16, linear LDS dest, PRE-SWIZZLED global
// source (octet c = cs ^ ((row>>1)&3)); fragment ds_read_b128 applies the
// same swizzle -> <=2-way bank aliasing (free).
template <int BM, bool ACC>
__global__ __launch_bounds__(256, 2) void gemm_sp(
    const unsigned short* __restrict__ Ah, const unsigned short* __restrict__ Al,
    const unsigned short* __restrict__ Bh, const unsigned short* __restrict__ Bl,
    float* __restrict__ C, int N, int K, int actsplit) {
    constexpr int WM = (BM == 128) ? 2 : 1;   // waves along M
    constexpr int WN = 4 / WM;                // waves along N
    constexpr int WNS = 128 / WN;             // wave N-extent (64 or 32)
    constexpr int NF = WNS / 16;              // N frags per wave (4 or 2)
    constexpr int AUNITS = BM * 4;            // 16B units per A buffer
    constexpr int AISS = BM / 64;             // A issues per lane (2 or 1)
    __shared__ __align__(16) char lds[(AUNITS * 2 + 1024) * 16];
    char* ldsAh = lds;
    char* ldsAl = lds + AUNITS * 16;
    char* ldsBh = lds + AUNITS * 32;
    char* ldsBl = lds + AUNITS * 32 + 8192;

    const int tid = threadIdx.x;
    const int lane = tid & 63, wave = tid >> 6;
    const int wm = (BM == 128) ? (wave >> 1) : 0;
    const int wn = (BM == 128) ? (wave & 1) : wave;
    const int lr = lane & 15, lg = lane >> 4;
    const int m0 = blockIdx.y * BM, n0 = blockIdx.x * 128;

    f32x4 zero = {0.f, 0.f, 0.f, 0.f};
    f32x4 acc[4][NF];
#pragma unroll
    for (int m = 0; m < 4; ++m)
#pragma unroll
        for (int n = 0; n < NF; ++n) acc[m][n] = zero;

    const int swz = (lr >> 1) & 3;  // frag-read octet swizzle

    for (int k0 = 0; k0 < K; k0 += 32) {
        // ---- stage A (hi, lo) ----
#pragma unroll
        for (int i = 0; i < AISS; ++i) {
            const int u = i * 256 + wave * 64 + lane;
            const int row = u >> 2, cs = u & 3;
            const int c = cs ^ ((row >> 1) & 3);
            const size_t goff = (size_t)(m0 + row) * K + k0 + c * 8;
            const int lbase = (i * 256 + wave * 64) * 16;
            __builtin_amdgcn_global_load_lds(
                (const __attribute__((address_space(1))) void*)(Ah + goff),
                (__attribute__((address_space(3))) void*)(ldsAh + lbase), 16, 0, 0);
            __builtin_amdgcn_global_load_lds(
                (const __attribute__((address_space(1))) void*)(Al + goff),
                (__attribute__((address_space(3))) void*)(ldsAl + lbase), 16, 0, 0);
        }
        // ---- stage B (hi, lo) ----
#pragma unroll
        for (int i = 0; i < 2; ++i) {
            const int u = i * 256 + wave * 64 + lane;
            const int row = u >> 2, cs = u & 3;
            const int c = cs ^ ((row >> 1) & 3);
            const size_t goff = (size_t)(n0 + row) * K + k0 + c * 8;
            const int lbase = (i * 256 + wave * 64) * 16;
            __builtin_amdgcn_global_load_lds(
                (const __attribute__((address_space(1))) void*)(Bh + goff),
                (__attribute__((address_space(3))) void*)(ldsBh + lbase), 16, 0, 0);
            __builtin_amdgcn_global_load_lds(
                (const __attribute__((address_space(1))) void*)(Bl + goff),
                (__attribute__((address_space(3))) void*)(ldsBl + lbase), 16, 0, 0);
        }
        __syncthreads();  // compiler emits vmcnt(0) drain before barrier
        bf16x8 fAh[4], fAl[4], fBh[NF], fBl[NF];
#pragma unroll
        for (int m = 0; m < 4; ++m) {
            const int row = wm * 64 + m * 16 + lr;
            const int u = row * 4 + (lg ^ swz);
            fAh[m] = *(const bf16x8*)(ldsAh + u * 16);
            fAl[m] = *(const bf16x8*)(ldsAl + u * 16);
        }
#pragma unroll
        for (int n = 0; n < NF; ++n) {
            const int row = wn * WNS + n * 16 + lr;
            const int u = row * 4 + (lg ^ swz);
            fBh[n] = *(const bf16x8*)(ldsBh + u * 16);
            fBl[n] = *(const bf16x8*)(ldsBl + u * 16);
        }
#pragma unroll
        for (int m = 0; m < 4; ++m)
#pragma unroll
            for (int n = 0; n < NF; ++n) {
                acc[m][n] = __builtin_amdgcn_mfma_f32_16x16x32_bf16(fAl[m], fBh[n], acc[m][n], 0, 0, 0);
                acc[m][n] = __builtin_amdgcn_mfma_f32_16x16x32_bf16(fAh[m], fBl[n], acc[m][n], 0, 0, 0);
                acc[m][n] = __builtin_amdgcn_mfma_f32_16x16x32_bf16(fAh[m], fBh[n], acc[m][n], 0, 0, 0);
            }
        __syncthreads();
    }
#pragma unroll
    for (int m = 0; m < 4; ++m) {
        const int row = m0 + wm * 64 + m * 16 + lg * 4;
#pragma unroll
        for (int n = 0; n < NF; ++n) {
            const int col = n0 + wn * WNS + n * 16 + lr;
            const bool act = col < actsplit;
            float* cp = C + (size_t)row * N + col;
#pragma unroll
            for (int j = 0; j < 4; ++j) {
                float v = acc[m][n][j];
                if (act) v = v / (1.0f + expf(-v));
                if (ACC) cp[(size_t)j * N] += v;
                else cp[(size_t)j * N] = v;
            }
        }
    }
}

// ---------------------------------------------------------------------------
// Post-QKV: qk-norm + rope; q -> bf16 [H][T][HD]; k -> keys fp32 + bf16 copy;
// v -> vals fp32. kvbuf is [T][2048]: k cols 0..1023, v cols 1024..2047.
__global__ __launch_bounds__(256) void qkv_post_k(
    const float* __restrict__ qbuf, const float* __restrict__ kvbuf,
    const float* __restrict__ qn, const float* __restrict__ kn,
    const float* __restrict__ cosT, const float* __restrict__ sinT,
    unsigned short* __restrict__ qb16, float* __restrict__ keys,
    unsigned short* __restrict__ kb16, float* __restrict__ vals) {
    const int r = blockIdx.x * 4 + (threadIdx.x >> 6);
    const int lane = threadIdx.x & 63;
    const int t = r >> 5, c = r & 31;
    if (c >= 24) {  // v: copy/transpose
        const int vh = c - 24;
        const float* src = kvbuf + (size_t)t * 2048 + 1024 + vh * 128;
        float* dst = vals + ((size_t)vh * SEQ + t) * 128;
        dst[lane] = src[lane];
        dst[lane + 64] = src[lane + 64];
        return;
    }
    const float* src;
    const float* nw;
    if (c < 16) { src = qbuf + (size_t)t * 2048 + c * 128; nw = qn; }
    else        { src = kvbuf + (size_t)t * 2048 + (c - 16) * 128; nw = kn; }
    float x1 = src[lane], x2 = src[lane + 64];
    float ss = x1 * x1 + x2 * x2;
#pragma unroll
    for (int off = 32; off >= 1; off >>= 1) ss += __shfl_xor(ss, off);
    float scale = rsqrtf(ss * (1.0f / HDIM) + RMS_EPS);
    float xn1 = x1 * scale * nw[lane];
    float xn2 = x2 * scale * nw[lane + 64];
    float cc = cosT[t * 64 + lane], sv = sinT[t * 64 + lane];
    float o1 = xn1 * cc - xn2 * sv;
    float o2 = xn2 * cc + xn1 * sv;
    if (c < 16) {
        unsigned short* dst = qb16 + ((size_t)c * SEQ + t) * 128;
        dst[lane] = f2bf(o1);
        dst[lane + 64] = f2bf(o2);
    } else {
        const int kh = c - 16;
        float* kd = keys + ((size_t)kh * SEQ + t) * 128;
        kd[lane] = o1;
        kd[lane + 64] = o2;
        unsigned short* kb = kb16 + ((size_t)kh * SEQ + t) * 128;
        kb[lane] = f2bf(o1);
        kb[lane + 64] = f2bf(o2);
    }
}

// ---------------------------------------------------------------------------
// V transpose: vals fp32 [KV][T][HD] -> vt bf16 [KV][HD][T]
__global__ __launch_bounds__(256) void vtrans_k(const float* __restrict__ vals,
                                                unsigned short* __restrict__ vt) {
    __shared__ float tile[32][33];
    const int t0 = blockIdx.x * 32, d0 = blockIdx.y * 32, kvh = blockIdx.z;
    const int a = threadIdx.x >> 3, b4 = (threadIdx.x & 7) * 4;
    const float4 v = *(const float4*)(vals + ((size_t)kvh * SEQ + t0 + a) * 128 + d0 + b4);
    tile[a][b4] = v.x; tile[a][b4 + 1] = v.y; tile[a][b4 + 2] = v.z; tile[a][b4 + 3] = v.w;
    __syncthreads();
    u16x4 o = {f2bf(tile[b4][a]), f2bf(tile[b4 + 1][a]), f2bf(tile[b4 + 2][a]), f2bf(tile[b4 + 3][a])};
    *(u16x4*)(vt + ((size_t)kvh * HDIM + d0 + a) * SEQ + t0 + b4) = o;
}

// ---------------------------------------------------------------------------
// Flash attention, bf16 MFMA, causal. Block: 4 waves, 128 q-rows (32/wave).
// S^T = mfma(K, Q): softmax over k is in-lane (8 vals) + 2 shuffles.
// P^T -> LDS (bf16, XOR-swizzled) -> O^T = mfma(V^T, P).
// Grid: (T/128, H).
__global__ __launch_bounds__(256, 2) void attn_k(
    const unsigned short* __restrict__ Qb, const unsigned short* __restrict__ Kb,
    const unsigned short* __restrict__ Vt,
    unsigned short* __restrict__ AOh, unsigned short* __restrict__ AOl) {
    __shared__ __align__(16) char lds[24576];  // K 8KB | Vt 8KB | P 4x2KB
    const int tid = threadIdx.x;
    const int wave = tid >> 6, lane = tid & 63;
    const int lr = lane & 15, lg = lane >> 4;
    const int head = blockIdx.y, kvh = head >> 1;
    const int qb = blockIdx.x * 128;
    const int qw = qb + wave * 32;
    char* Klds = lds;
    char* Vlds = lds + 8192;
    char* Plds = lds + 16384 + wave * 2048;

    bf16x8 qf[2][4];
#pragma unroll
    for (int qg = 0; qg < 2; ++qg)
#pragma unroll
        for (int ds = 0; ds < 4; ++ds)
            qf[qg][ds] = *(const bf16x8*)(Qb + ((size_t)head * SEQ + qw + qg * 16 + lr) * 128 + ds * 32 + lg * 8);

    f32x4 zero = {0.f, 0.f, 0.f, 0.f};
    f32x4 oacc[2][8];
#pragma unroll
    for (int qg = 0; qg < 2; ++qg)
#pragma unroll
        for (int dg = 0; dg < 8; ++dg) oacc[qg][dg] = zero;
    float m_r[2] = {NEGINF, NEGINF};
    float l_r[2] = {0.f, 0.f};

    const int s_k0 = tid >> 4, s_db = tid & 15;  // K staging: (k, dblk)
    const int s_d0 = tid >> 2, s_kb = tid & 3;   // V staging: (d, kblk)

    const int nkv = (qb >> 5) + 4;
    for (int kv = 0; kv < nkv; ++kv) {
        const int k0 = kv * 32;
        __syncthreads();
        {
            bf16x8 t0 = *(const bf16x8*)(Kb + ((size_t)kvh * SEQ + k0 + s_k0) * 128 + s_db * 8);
            bf16x8 t1 = *(const bf16x8*)(Kb + ((size_t)kvh * SEQ + k0 + s_k0 + 16) * 128 + s_db * 8);
            *(bf16x8*)(Klds + ((s_k0 * 256 + s_db * 16) ^ ((s_k0 & 7) << 4))) = t0;
            *(bf16x8*)(Klds + (((s_k0 + 16) * 256 + s_db * 16) ^ (((s_k0 + 16) & 7) << 4))) = t1;
            bf16x8 v0 = *(const bf16x8*)(Vt + ((size_t)kvh * HDIM + s_d0) * SEQ + k0 + s_kb * 8);
            bf16x8 v1 = *(const bf16x8*)(Vt + ((size_t)kvh * HDIM + s_d0 + 64) * SEQ + k0 + s_kb * 8);
            *(bf16x8*)(Vlds + ((s_d0 * 64 + s_kb * 16) ^ ((s_d0 & 7) << 4))) = v0;
            *(bf16x8*)(Vlds + (((s_d0 + 64) * 64 + s_kb * 16) ^ (((s_d0 + 64) & 7) << 4))) = v1;
        }
        __syncthreads();
        // S^T[k][q]
        f32x4 S[2][2];
        S[0][0] = zero; S[0][1] = zero; S[1][0] = zero; S[1][1] = zero;
#pragma unroll
        for (int ds = 0; ds < 4; ++ds) {
#pragma unroll
            for (int kg = 0; kg < 2; ++kg) {
                const int krow = kg * 16 + lr;
                bf16x8 kf = *(const bf16x8*)(Klds + ((krow * 256 + ds * 64 + lg * 16) ^ ((krow & 7) << 4)));
                S[kg][0] = __builtin_amdgcn_mfma_f32_16x16x32_bf16(kf, qf[0][ds], S[kg][0], 0, 0, 0);
                S[kg][1] = __builtin_amdgcn_mfma_f32_16x16x32_bf16(kf, qf[1][ds], S[kg][1], 0, 0, 0);
            }
        }
        // online softmax per q-column (q = qw + qg*16 + lr)
#pragma unroll
        for (int qg = 0; qg < 2; ++qg) {
            const int q = qw + qg * 16 + lr;
            float p[2][4];
            float mm = NEGINF;
#pragma unroll
            for (int kg = 0; kg < 2; ++kg)
#pragma unroll
                for (int j = 0; j < 4; ++j) {
                    const int kk = k0 + kg * 16 + lg * 4 + j;
                    float s = S[kg][qg][j] * SC2;
                    s = (kk <= q) ? s : NEGINF;
                    p[kg][j] = s;
                    mm = fmaxf(mm, s);
                }
            mm = fmaxf(mm, __shfl_xor(mm, 16));
            mm = fmaxf(mm, __shfl_xor(mm, 32));
            const float mnew = fmaxf(m_r[qg], mm);
            const float alpha = exp2f(m_r[qg] - mnew);
            m_r[qg] = mnew;
            float ps = 0.f;
#pragma unroll
            for (int kg = 0; kg < 2; ++kg)
#pragma unroll
                for (int j = 0; j < 4; ++j) {
                    float e = exp2f(p[kg][j] - mnew);
                    p[kg][j] = e;
                    ps += e;
                }
            ps += __shfl_xor(ps, 16);
            ps += __shfl_xor(ps, 32);
            l_r[qg] = l_r[qg] * alpha + ps;
#pragma unroll
            for (int dg = 0; dg < 8; ++dg) oacc[qg][dg] *= alpha;
            const int qloc = qg * 16 + lr;
#pragma unroll
            for (int kg = 0; kg < 2; ++kg)
#pragma unroll
                for (int j = 0; j < 4; ++j) {
                    const int kloc = kg * 16 + lg * 4 + j;
                    *(unsigned short*)(Plds + ((qloc * 64 + kloc * 2) ^ ((qloc & 7) << 4))) = f2bf(p[kg][j]);
                }
        }
        // PV: O^T[d][q] += V^T * P
        bf16x8 pf[2];
#pragma unroll
        for (int qg = 0; qg < 2; ++qg) {
            const int qloc = qg * 16 + lr;
            pf[qg] = *(const bf16x8*)(Plds + ((qloc * 64 + lg * 16) ^ ((qloc & 7) << 4)));
        }
#pragma unroll
        for (int dg = 0; dg < 8; ++dg) {
            const int drow = dg * 16 + lr;
            bf16x8 vf = *(const bf16x8*)(Vlds + ((drow * 64 + lg * 16) ^ ((drow & 7) << 4)));
            oacc[0][dg] = __builtin_amdgcn_mfma_f32_16x16x32_bf16(vf, pf[0], oacc[0][dg], 0, 0, 0);
            oacc[1][dg] = __builtin_amdgcn_mfma_f32_16x16x32_bf16(vf, pf[1], oacc[1][dg], 0, 0, 0);
        }
    }
    const float inv0 = 1.0f / l_r[0];
    const float inv1 = 1.0f / l_r[1];
#pragma unroll
    for (int qg = 0; qg < 2; ++qg) {
        const float iv = qg ? inv1 : inv0;
        const int t = qw + qg * 16 + lr;
#pragma unroll
        for (int dg = 0; dg < 8; ++dg) {
            const int col = head * 128 + dg * 16 + lg * 4;
            float v0 = oacc[qg][dg][0] * iv, v1 = oacc[qg][dg][1] * iv;
            float v2 = oacc[qg][dg][2] * iv, v3 = oacc[qg][dg][3] * iv;
            unsigned short h0, h1, h2, h3, l0, l1, l2, l3;
            fsplit(v0, h0, l0); fsplit(v1, h1, l1); fsplit(v2, h2, l2); fsplit(v3, h3, l3);
            u16x4 hh = {h0, h1, h2, h3};
            u16x4 ll = {l0, l1, l2, l3};
            *(u16x4*)(AOh + (size_t)t * 2048 + col) = hh;
            *(u16x4*)(AOl + (size_t)t * 2048 + col) = ll;
        }
    }
}

// ---------------------------------------------------------------------------
// gated product: p = g * u (g pre-silu'd by GEMM epilogue), split output
__global__ __launch_bounds__(256) void mulsplit_k(const float* __restrict__ gu,
                                                  unsigned short* __restrict__ ph,
                                                  unsigned short* __restrict__ pl) {
    const int c4 = blockIdx.x * 256 + threadIdx.x;  // 0..767
    const int row = blockIdx.y;
    const float* base = gu + (size_t)row * 6144;
    float4 g = *(const float4*)(base + c4 * 4);
    float4 u = *(const float4*)(base + 3072 + c4 * 4);
    float p0 = g.x * u.x, p1 = g.y * u.y, p2 = g.z * u.z, p3 = g.w * u.w;
    unsigned short h0, h1, h2, h3, l0, l1, l2, l3;
    fsplit(p0, h0, l0); fsplit(p1, h1, l1); fsplit(p2, h2, l2); fsplit(p3, h3, l3);
    u16x4 hh = {h0, h1, h2, h3};
    u16x4 ll = {l0, l1, l2, l3};
    *(u16x4*)(ph + (size_t)row * 3072 + c4 * 4) = hh;
    *(u16x4*)(pl + (size_t)row * 3072 + c4 * 4) = ll;
}

// ---------------------------------------------------------------------------
extern "C" void kernel_launch(void* const* d_in, const int* in_sizes, int n_in,
                              void* d_out, int out_size, void* d_ws, size_t ws_size,
                              hipStream_t stream) {
    const float* emb = (const float*)d_in[0];
    const float* ln1 = (const float*)d_in[1];
    const float* qw  = (const float*)d_in[2];
    const float* kw  = (const float*)d_in[3];
    const float* vw  = (const float*)d_in[4];
    const float* qn  = (const float*)d_in[5];
    const float* kn  = (const float*)d_in[6];
    const float* ow  = (const float*)d_in[7];
    const float* ln2 = (const float*)d_in[8];
    const float* gw  = (const float*)d_in[9];
    const float* uw  = (const float*)d_in[10];
    const float* dw  = (const float*)d_in[11];
    const float* nw  = (const float*)d_in[12];

    float* out  = (float*)d_out;
    float* keys = out + (size_t)SEQ * DMODEL;
    float* vals = keys + (size_t)LAYERS * NKV * SEQ * HDIM;

    // ws layout (total 113 MiB; gu aliases 16..64 MiB, ph/pl alias 64..88 MiB)
    char* W = (char*)d_ws;
    float* h             = (float*)(W);
    unsigned short* xh   = (unsigned short*)(W + (8ull << 20));
    unsigned short* xl   = (unsigned short*)(W + (12ull << 20));
    float* qbuf          = (float*)(W + (16ull << 20));
    float* kvbuf         = (float*)(W + (32ull << 20));
    unsigned short* qb16 = (unsigned short*)(W + (48ull << 20));
    unsigned short* kb16 = (unsigned short*)(W + (56ull << 20));
    unsigned short* vt16 = (unsigned short*)(W + (60ull << 20));
    unsigned short* aoh  = (unsigned short*)(W + (64ull << 20));
    unsigned short* aol  = (unsigned short*)(W + (72ull << 20));
    float* gu            = (float*)(W + (16ull << 20));           // alias
    unsigned short* ph   = (unsigned short*)(W + (64ull << 20));  // alias
    unsigned short* pl   = (unsigned short*)(W + (76ull << 20));  // alias
    unsigned short* wh   = (unsigned short*)(W + (88ull << 20));
    unsigned short* wl   = (unsigned short*)(W + (100ull << 20));
    float* cosT          = (float*)(W + (112ull << 20));
    float* sinT          = cosT + SEQ * 64;

    hipMemcpyAsync(h, emb, sizeof(float) * SEQ * DMODEL, hipMemcpyDeviceToDevice, stream);
    rope_init_k<<<SEQ, 64, 0, stream>>>(cosT, sinT);

    for (int i = 0; i < LAYERS; ++i) {
        float* keys_i = keys + (size_t)i * NKV * SEQ * HDIM;
        float* vals_i = vals + (size_t)i * NKV * SEQ * HDIM;
        // ln1 -> x (split)
        rms_k<true><<<SEQ, 256, 0, stream>>>(h, ln1 + (size_t)i * DMODEL, nullptr, xh, xl);
        // q proj
        convert_w_k<<<2048, 256, 0, stream>>>(qw + (size_t)i * 2097152, wh, wl, 524288);
        gemm_sp<128, false><<<dim3(16, 16), 256, 0, stream>>>(xh, xl, wh, wl, qbuf, 2048, 1024, 0);
        // k,v proj fused (B rows 0..1023 = k_w, 1024..2047 = v_w)
        convert_w_k<<<1024, 256, 0, stream>>>(kw + (size_t)i * 1048576, wh, wl, 262144);
        convert_w_k<<<1024, 256, 0, stream>>>(vw + (size_t)i * 1048576, wh + 1048576, wl + 1048576, 262144);
        gemm_sp<128, false><<<dim3(16, 16), 256, 0, stream>>>(xh, xl, wh, wl, kvbuf, 2048, 1024, 0);
        // qk-norm + rope + layout
        qkv_post_k<<<SEQ * 32 / 4, 256, 0, stream>>>(qbuf, kvbuf, qn + (size_t)i * HDIM,
                                                     kn + (size_t)i * HDIM, cosT, sinT,
                                                     qb16, keys_i, kb16, vals_i);
        vtrans_k<<<dim3(SEQ / 32, HDIM / 32, NKV), 256, 0, stream>>>(vals_i, vt16);
        attn_k<<<dim3(SEQ / 128, NH), 256, 0, stream>>>(qb16, kb16, vt16, aoh, aol);
        // o proj (accumulate into h), BM=64 for full-chip grid (8x32=256 blocks)
        convert_w_k<<<2048, 256, 0, stream>>>(ow + (size_t)i * 2097152, wh, wl, 524288);
        gemm_sp<64, true><<<dim3(8, 32), 256, 0, stream>>>(aoh, aol, wh, wl, h, 1024, 2048, 0);
        // ln2 -> x (split)
        rms_k<true><<<SEQ, 256, 0, stream>>>(h, ln2 + (size_t)i * DMODEL, nullptr, xh, xl);
        // gate+up fused (rows 0..3071 = gate w/ silu, 3072..6143 = up)
        convert_w_k<<<3072, 256, 0, stream>>>(gw + (size_t)i * 3145728, wh, wl, 786432);
        convert_w_k<<<3072, 256, 0, stream>>>(uw + (size_t)i * 3145728, wh + 3145728, wl + 3145728, 786432);
        gemm_sp<128, false><<<dim3(48, 16), 256, 0, stream>>>(xh, xl, wh, wl, gu, 6144, 1024, 3072);
        mulsplit_k<<<dim3(3, SEQ), 256, 0, stream>>>(gu, ph, pl);
        // down proj (accumulate into h), BM=64
        convert_w_k<<<3072, 256, 0, stream>>>(dw + (size_t)i * 3145728, wh, wl, 786432);
        gemm_sp<64, true><<<dim3(8, 32), 256, 0, stream>>>(ph, pl, wh, wl, h, 1024, 3072, 0);
    }
    // final norm -> hs
    rms_k<false><<<SEQ, 256, 0, stream>>>(h, nw, out, nullptr, nullptr);
}

// Round 5
// 2750.705 us; speedup vs baseline: 3.5968x; 1.0516x over previous
//
#include <hip/hip_runtime.h>
#include <hip/hip_bf16.h>
#include <math.h>

#define LAYERS 5
#define DMODEL 1024
#define NH 16
#define NKV 8
#define HDIM 128
#define FFD 3072
#define SEQ 2048
#define RMS_EPS 1e-6f
// ATT_SCALE * log2(e):  0.08838834764831845 * 1.4426950408889634
#define SC2 0.12753292444440332f
#define NEGINF (-1e30f)

typedef __attribute__((ext_vector_type(8))) short bf16x8;
typedef __attribute__((ext_vector_type(4))) float f32x4;
typedef __attribute__((ext_vector_type(4))) unsigned short u16x4;

__device__ __forceinline__ unsigned short f2bf(float x) {
    unsigned int u = __float_as_uint(x);
    u = (u + 0x7fffu + ((u >> 16) & 1u)) >> 16;
    return (unsigned short)u;
}
__device__ __forceinline__ float bf2f(unsigned short b) {
    return __uint_as_float(((unsigned int)b) << 16);
}
__device__ __forceinline__ void fsplit(float x, unsigned short &h, unsigned short &l) {
    h = f2bf(x);
    l = f2bf(x - bf2f(h));
}

// ---------------------------------------------------------------------------
// RoPE tables (T x 64)
__global__ void rope_init_k(float* __restrict__ cosT, float* __restrict__ sinT) {
    int t = blockIdx.x;
    int j = threadIdx.x;  // 0..63
    double inv = pow(1.0e6, -((double)j) / 64.0);
    float angf = (float)t * (float)inv;
    double ang = (double)angf;
    cosT[t * 64 + j] = (float)cos(ang);
    sinT[t * 64 + j] = (float)sin(ang);
}

// ---------------------------------------------------------------------------
// RMSNorm over D=1024. SPLIT: write bf16 hi/lo pair; else fp32.
template <bool SPLIT>
__global__ __launch_bounds__(256) void rms_k(const float* __restrict__ in,
                                             const float* __restrict__ w,
                                             float* __restrict__ outf,
                                             unsigned short* __restrict__ oh,
                                             unsigned short* __restrict__ ol) {
    __shared__ float red[4];
    const int row = blockIdx.x;
    const int t = threadIdx.x;
    const float* p = in + (size_t)row * DMODEL;
    float4 v = *(const float4*)(p + t * 4);
    float ss = v.x * v.x + v.y * v.y + v.z * v.z + v.w * v.w;
#pragma unroll
    for (int off = 32; off >= 1; off >>= 1) ss += __shfl_xor(ss, off);
    if ((t & 63) == 0) red[t >> 6] = ss;
    __syncthreads();
    float tot = red[0] + red[1] + red[2] + red[3];
    float scale = rsqrtf(tot * (1.0f / DMODEL) + RMS_EPS);
    float4 w4 = *(const float4*)(w + t * 4);
    float o0 = v.x * scale * w4.x;
    float o1 = v.y * scale * w4.y;
    float o2 = v.z * scale * w4.z;
    float o3 = v.w * scale * w4.w;
    if (SPLIT) {
        unsigned short h0, h1, h2, h3, l0, l1, l2, l3;
        fsplit(o0, h0, l0); fsplit(o1, h1, l1); fsplit(o2, h2, l2); fsplit(o3, h3, l3);
        u16x4 hh = {h0, h1, h2, h3};
        u16x4 ll = {l0, l1, l2, l3};
        *(u16x4*)(oh + (size_t)row * DMODEL + t * 4) = hh;
        *(u16x4*)(ol + (size_t)row * DMODEL + t * 4) = ll;
    } else {
        float4 o = {o0, o1, o2, o3};
        *(float4*)(outf + (size_t)row * DMODEL + t * 4) = o;
    }
}

// ---------------------------------------------------------------------------
// fp32 -> bf16 hi/lo split (weights), float4 granularity
__global__ __launch_bounds__(256) void convert_w_k(const float* __restrict__ src,
                                                   unsigned short* __restrict__ hi,
                                                   unsigned short* __restrict__ lo,
                                                   int n4) {
    int i = blockIdx.x * 256 + threadIdx.x;
    if (i >= n4) return;
    float4 v = ((const float4*)src)[i];
    unsigned short h0, h1, h2, h3, l0, l1, l2, l3;
    fsplit(v.x, h0, l0); fsplit(v.y, h1, l1); fsplit(v.z, h2, l2); fsplit(v.w, h3, l3);
    u16x4 hh = {h0, h1, h2, h3};
    u16x4 ll = {l0, l1, l2, l3};
    ((u16x4*)hi)[i] = hh;
    ((u16x4*)lo)[i] = ll;
}

// ---------------------------------------------------------------------------
// Split-precision bf16 MFMA GEMM:  C[m][n] (+)= act( sum_k A[m][k]*B[n][k] )
template <int BM, bool ACC>
__global__ __launch_bounds__(256, 2) void gemm_sp(
    const unsigned short* __restrict__ Ah, const unsigned short* __restrict__ Al,
    const unsigned short* __restrict__ Bh, const unsigned short* __restrict__ Bl,
    float* __restrict__ C, int N, int K, int actsplit) {
    constexpr int WM = (BM == 128) ? 2 : 1;   // waves along M
    constexpr int WN = 4 / WM;                // waves along N
    constexpr int WNS = 128 / WN;             // wave N-extent (64 or 32)
    constexpr int NF = WNS / 16;              // N frags per wave (4 or 2)
    constexpr int AUNITS = BM * 4;            // 16B units per A buffer
    constexpr int AISS = BM / 64;             // A issues per lane (2 or 1)
    __shared__ __align__(16) char lds[(AUNITS * 2 + 1024) * 16];
    char* ldsAh = lds;
    char* ldsAl = lds + AUNITS * 16;
    char* ldsBh = lds + AUNITS * 32;
    char* ldsBl = lds + AUNITS * 32 + 8192;

    const int tid = threadIdx.x;
    const int lane = tid & 63, wave = tid >> 6;
    const int wm = (BM == 128) ? (wave >> 1) : 0;
    const int wn = (BM == 128) ? (wave & 1) : wave;
    const int lr = lane & 15, lg = lane >> 4;
    const int m0 = blockIdx.y * BM, n0 = blockIdx.x * 128;

    f32x4 zero = {0.f, 0.f, 0.f, 0.f};
    f32x4 acc[4][NF];
#pragma unroll
    for (int m = 0; m < 4; ++m)
#pragma unroll
        for (int n = 0; n < NF; ++n) acc[m][n] = zero;

    const int swz = (lr >> 1) & 3;  // frag-read octet swizzle

    for (int k0 = 0; k0 < K; k0 += 32) {
        // ---- stage A (hi, lo) ----
#pragma unroll
        for (int i = 0; i < AISS; ++i) {
            const int u = i * 256 + wave * 64 + lane;
            const int row = u >> 2, cs = u & 3;
            const int c = cs ^ ((row >> 1) & 3);
            const size_t goff = (size_t)(m0 + row) * K + k0 + c * 8;
            const int lbase = (i * 256 + wave * 64) * 16;
            __builtin_amdgcn_global_load_lds(
                (const __attribute__((address_space(1))) void*)(Ah + goff),
                (__attribute__((address_space(3))) void*)(ldsAh + lbase), 16, 0, 0);
            __builtin_amdgcn_global_load_lds(
                (const __attribute__((address_space(1))) void*)(Al + goff),
                (__attribute__((address_space(3))) void*)(ldsAl + lbase), 16, 0, 0);
        }
        // ---- stage B (hi, lo) ----
#pragma unroll
        for (int i = 0; i < 2; ++i) {
            const int u = i * 256 + wave * 64 + lane;
            const int row = u >> 2, cs = u & 3;
            const int c = cs ^ ((row >> 1) & 3);
            const size_t goff = (size_t)(n0 + row) * K + k0 + c * 8;
            const int lbase = (i * 256 + wave * 64) * 16;
            __builtin_amdgcn_global_load_lds(
                (const __attribute__((address_space(1))) void*)(Bh + goff),
                (__attribute__((address_space(3))) void*)(ldsBh + lbase), 16, 0, 0);
            __builtin_amdgcn_global_load_lds(
                (const __attribute__((address_space(1))) void*)(Bl + goff),
                (__attribute__((address_space(3))) void*)(ldsBl + lbase), 16, 0, 0);
        }
        __syncthreads();
        bf16x8 fAh[4], fAl[4], fBh[NF], fBl[NF];
#pragma unroll
        for (int m = 0; m < 4; ++m) {
            const int row = wm * 64 + m * 16 + lr;
            const int u = row * 4 + (lg ^ swz);
            fAh[m] = *(const bf16x8*)(ldsAh + u * 16);
            fAl[m] = *(const bf16x8*)(ldsAl + u * 16);
        }
#pragma unroll
        for (int n = 0; n < NF; ++n) {
            const int row = wn * WNS + n * 16 + lr;
            const int u = row * 4 + (lg ^ swz);
            fBh[n] = *(const bf16x8*)(ldsBh + u * 16);
            fBl[n] = *(const bf16x8*)(ldsBl + u * 16);
        }
#pragma unroll
        for (int m = 0; m < 4; ++m)
#pragma unroll
            for (int n = 0; n < NF; ++n) {
                acc[m][n] = __builtin_amdgcn_mfma_f32_16x16x32_bf16(fAl[m], fBh[n], acc[m][n], 0, 0, 0);
                acc[m][n] = __builtin_amdgcn_mfma_f32_16x16x32_bf16(fAh[m], fBl[n], acc[m][n], 0, 0, 0);
                acc[m][n] = __builtin_amdgcn_mfma_f32_16x16x32_bf16(fAh[m], fBh[n], acc[m][n], 0, 0, 0);
            }
        __syncthreads();
    }
#pragma unroll
    for (int m = 0; m < 4; ++m) {
        const int row = m0 + wm * 64 + m * 16 + lg * 4;
#pragma unroll
        for (int n = 0; n < NF; ++n) {
            const int col = n0 + wn * WNS + n * 16 + lr;
            const bool act = col < actsplit;
            float* cp = C + (size_t)row * N + col;
#pragma unroll
            for (int j = 0; j < 4; ++j) {
                float v = acc[m][n][j];
                if (act) v = v / (1.0f + expf(-v));
                if (ACC) cp[(size_t)j * N] += v;
                else cp[(size_t)j * N] = v;
            }
        }
    }
}

// ---------------------------------------------------------------------------
// Post-QKV: qk-norm + rope; q -> bf16 [H][T][HD]; k -> keys fp32 + bf16 copy;
// v -> vals fp32. kvbuf is [T][2048]: k cols 0..1023, v cols 1024..2047.
__global__ __launch_bounds__(256) void qkv_post_k(
    const float* __restrict__ qbuf, const float* __restrict__ kvbuf,
    const float* __restrict__ qn, const float* __restrict__ kn,
    const float* __restrict__ cosT, const float* __restrict__ sinT,
    unsigned short* __restrict__ qb16, float* __restrict__ keys,
    unsigned short* __restrict__ kb16, float* __restrict__ vals) {
    const int r = blockIdx.x * 4 + (threadIdx.x >> 6);
    const int lane = threadIdx.x & 63;
    const int t = r >> 5, c = r & 31;
    if (c >= 24) {  // v: copy/transpose
        const int vh = c - 24;
        const float* src = kvbuf + (size_t)t * 2048 + 1024 + vh * 128;
        float* dst = vals + ((size_t)vh * SEQ + t) * 128;
        dst[lane] = src[lane];
        dst[lane + 64] = src[lane + 64];
        return;
    }
    const float* src;
    const float* nw;
    if (c < 16) { src = qbuf + (size_t)t * 2048 + c * 128; nw = qn; }
    else        { src = kvbuf + (size_t)t * 2048 + (c - 16) * 128; nw = kn; }
    float x1 = src[lane], x2 = src[lane + 64];
    float ss = x1 * x1 + x2 * x2;
#pragma unroll
    for (int off = 32; off >= 1; off >>= 1) ss += __shfl_xor(ss, off);
    float scale = rsqrtf(ss * (1.0f / HDIM) + RMS_EPS);
    float xn1 = x1 * scale * nw[lane];
    float xn2 = x2 * scale * nw[lane + 64];
    float cc = cosT[t * 64 + lane], sv = sinT[t * 64 + lane];
    float o1 = xn1 * cc - xn2 * sv;
    float o2 = xn2 * cc + xn1 * sv;
    if (c < 16) {
        unsigned short* dst = qb16 + ((size_t)c * SEQ + t) * 128;
        dst[lane] = f2bf(o1);
        dst[lane + 64] = f2bf(o2);
    } else {
        const int kh = c - 16;
        float* kd = keys + ((size_t)kh * SEQ + t) * 128;
        kd[lane] = o1;
        kd[lane + 64] = o2;
        unsigned short* kb = kb16 + ((size_t)kh * SEQ + t) * 128;
        kb[lane] = f2bf(o1);
        kb[lane + 64] = f2bf(o2);
    }
}

// ---------------------------------------------------------------------------
// V transpose: vals fp32 [KV][T][HD] -> vt bf16 [KV][HD][T]
__global__ __launch_bounds__(256) void vtrans_k(const float* __restrict__ vals,
                                                unsigned short* __restrict__ vt) {
    __shared__ float tile[32][33];
    const int t0 = blockIdx.x * 32, d0 = blockIdx.y * 32, kvh = blockIdx.z;
    const int a = threadIdx.x >> 3, b4 = (threadIdx.x & 7) * 4;
    const float4 v = *(const float4*)(vals + ((size_t)kvh * SEQ + t0 + a) * 128 + d0 + b4);
    tile[a][b4] = v.x; tile[a][b4 + 1] = v.y; tile[a][b4 + 2] = v.z; tile[a][b4 + 3] = v.w;
    __syncthreads();
    u16x4 o = {f2bf(tile[b4][a]), f2bf(tile[b4 + 1][a]), f2bf(tile[b4 + 2][a]), f2bf(tile[b4 + 3][a])};
    *(u16x4*)(vt + ((size_t)kvh * HDIM + d0 + a) * SEQ + t0 + b4) = o;
}

// ---------------------------------------------------------------------------
// Flash attention v2: bf16 MFMA, causal, KVBLK=64, double-buffered
// global_load_lds staging with counted vmcnt + raw barriers.
// Block: 128 thr (2 waves), 64 q-rows (32/wave). Grid: (T/64, H) = 512 blocks.
// LDS: K dbuf 2x16KB | V dbuf 2x16KB | P 2x4KB = 72KB -> 2 blocks/CU.
// K LDS: [64 row][16 unit16B], unit ^= row&7 (src pre-swizzled, read same).
// V LDS: [128 d][8 unit16B], unit ^= d&7.  P: [32 q][128B] ^ ((q&7)<<4).
__global__ __launch_bounds__(128, 1) void attn_k(
    const unsigned short* __restrict__ Qb, const unsigned short* __restrict__ Kb,
    const unsigned short* __restrict__ Vt,
    unsigned short* __restrict__ AOh, unsigned short* __restrict__ AOl) {
    __shared__ __align__(16) char lds[73728];
    const int tid = threadIdx.x;
    const int wave = tid >> 6, lane = tid & 63;
    const int lr = lane & 15, lg = lane >> 4;
    const int head = blockIdx.y, kvh = head >> 1;
    const int qtile = blockIdx.x;
    const int qw = qtile * 64 + wave * 32;
    char* Pw = lds + 65536 + wave * 4096;
    const size_t kbase = (size_t)kvh * SEQ;          // K rows base
    const size_t vtb = (size_t)kvh * HDIM;           // V^T rows base

    // Q fragments (2 qg x 4 d-slices), held in registers for the whole block
    bf16x8 qf[2][4];
#pragma unroll
    for (int qg = 0; qg < 2; ++qg)
#pragma unroll
        for (int ds = 0; ds < 4; ++ds)
            qf[qg][ds] = *(const bf16x8*)(Qb + ((size_t)head * SEQ + qw + qg * 16 + lr) * 128 + ds * 32 + lg * 8);

    f32x4 zero = {0.f, 0.f, 0.f, 0.f};
    f32x4 oacc[2][8];
#pragma unroll
    for (int qg = 0; qg < 2; ++qg)
#pragma unroll
        for (int dg = 0; dg < 8; ++dg) oacc[qg][dg] = zero;
    float m_r[2] = {NEGINF, NEGINF};
    float l_r[2] = {0.f, 0.f};

    // stage one 64-kv tile into buffer b (16 gload_lds of 16B per wave)
    auto stage = [&](int k0, int b) {
        const int kOff = b ? 16384 : 0;
        const int vOff = b ? 49152 : 32768;
#pragma unroll
        for (int i = 0; i < 8; ++i) {
            const int L = (i * 2 + wave) * 64 + lane;
            const int row = L >> 4, u = L & 15;
            const unsigned short* src = Kb + (kbase + k0 + row) * 128 + ((u ^ (row & 7)) << 3);
            __builtin_amdgcn_global_load_lds(
                (const __attribute__((address_space(1))) void*)src,
                (__attribute__((address_space(3))) void*)(lds + kOff + ((i * 2 + wave) << 10)), 16, 0, 0);
        }
#pragma unroll
        for (int i = 0; i < 8; ++i) {
            const int L = (i * 2 + wave) * 64 + lane;
            const int row = L >> 3, u = L & 7;
            const unsigned short* src = Vt + (vtb + row) * 2048 + k0 + ((u ^ (row & 7)) << 3);
            __builtin_amdgcn_global_load_lds(
                (const __attribute__((address_space(1))) void*)src,
                (__attribute__((address_space(3))) void*)(lds + vOff + ((i * 2 + wave) << 10)), 16, 0, 0);
        }
    };

    const int nsteps = qtile + 1;
    stage(0, 0);
    for (int s = 0; s < nsteps; ++s) {
        const int cur = s & 1;
        const int k0 = s * 64;
        if (s + 1 < nsteps) {
            stage((s + 1) * 64, cur ^ 1);
            asm volatile("s_waitcnt vmcnt(16)" ::: "memory");
        } else {
            asm volatile("s_waitcnt vmcnt(0)" ::: "memory");
        }
        __builtin_amdgcn_s_barrier();

        const int kOff = cur ? 16384 : 0;
        const int vOff = cur ? 49152 : 32768;
        // ---- QK^T: S^T[k][q] ----
        f32x4 S[4][2];
#pragma unroll
        for (int kg = 0; kg < 4; ++kg) { S[kg][0] = zero; S[kg][1] = zero; }
        __builtin_amdgcn_s_setprio(1);
#pragma unroll
        for (int ds = 0; ds < 4; ++ds) {
#pragma unroll
            for (int kg = 0; kg < 4; ++kg) {
                const int krow = kg * 16 + lr;
                bf16x8 kf = *(const bf16x8*)(lds + kOff + ((krow * 16 + ((ds * 4 + lg) ^ (krow & 7))) << 4));
                S[kg][0] = __builtin_amdgcn_mfma_f32_16x16x32_bf16(kf, qf[0][ds], S[kg][0], 0, 0, 0);
                S[kg][1] = __builtin_amdgcn_mfma_f32_16x16x32_bf16(kf, qf[1][ds], S[kg][1], 0, 0, 0);
            }
        }
        __builtin_amdgcn_s_setprio(0);
        // ---- online softmax (per q = col) ----
        const bool diag = (s == qtile);
#pragma unroll
        for (int qg = 0; qg < 2; ++qg) {
            const int q = qw + qg * 16 + lr;
            float p[4][4];
            float mm = NEGINF;
#pragma unroll
            for (int kg = 0; kg < 4; ++kg)
#pragma unroll
                for (int j = 0; j < 4; ++j) {
                    float sv = S[kg][qg][j] * SC2;
                    if (diag) {
                        const int kk = k0 + kg * 16 + lg * 4 + j;
                        sv = (kk <= q) ? sv : NEGINF;
                    }
                    p[kg][j] = sv;
                    mm = fmaxf(mm, sv);
                }
            mm = fmaxf(mm, __shfl_xor(mm, 16));
            mm = fmaxf(mm, __shfl_xor(mm, 32));
            if (!__all(mm <= m_r[qg] + 11.5f)) {  // defer-max: skip tiny growth
                const float mnew = fmaxf(m_r[qg], mm);
                const float alpha = exp2f(m_r[qg] - mnew);
                l_r[qg] *= alpha;
#pragma unroll
                for (int dg = 0; dg < 8; ++dg) oacc[qg][dg] *= alpha;
                m_r[qg] = mnew;
            }
            float ps = 0.f;
            const int qloc = qg * 16 + lr;
#pragma unroll
            for (int kg = 0; kg < 4; ++kg) {
                u16x4 pw;
#pragma unroll
                for (int j = 0; j < 4; ++j) {
                    const float e = exp2f(p[kg][j] - m_r[qg]);
                    ps += e;
                    pw[j] = f2bf(e);
                }
                *(u16x4*)(Pw + ((qloc * 128 + kg * 32 + lg * 8) ^ ((lr & 7) << 4))) = pw;
            }
            ps += __shfl_xor(ps, 16);
            ps += __shfl_xor(ps, 32);
            l_r[qg] += ps;
        }
        asm volatile("s_waitcnt lgkmcnt(0)" ::: "memory");
        // ---- PV: O^T[d][q] += V^T * P ----
        bf16x8 pf[2][2];
#pragma unroll
        for (int qg = 0; qg < 2; ++qg)
#pragma unroll
            for (int ks = 0; ks < 2; ++ks) {
                const int qloc = qg * 16 + lr;
                pf[qg][ks] = *(const bf16x8*)(Pw + ((qloc * 128 + ks * 64 + lg * 16) ^ ((lr & 7) << 4)));
            }
        __builtin_amdgcn_s_setprio(1);
#pragma unroll
        for (int dg = 0; dg < 8; ++dg) {
            const int drow = dg * 16 + lr;
#pragma unroll
            for (int ks = 0; ks < 2; ++ks) {
                bf16x8 vf = *(const bf16x8*)(lds + vOff + ((drow * 8 + ((ks * 4 + lg) ^ (drow & 7))) << 4));
                oacc[0][dg] = __builtin_amdgcn_mfma_f32_16x16x32_bf16(vf, pf[0][ks], oacc[0][dg], 0, 0, 0);
                oacc[1][dg] = __builtin_amdgcn_mfma_f32_16x16x32_bf16(vf, pf[1][ks], oacc[1][dg], 0, 0, 0);
            }
        }
        __builtin_amdgcn_s_setprio(0);
        __builtin_amdgcn_s_barrier();  // all reads of buf[cur] done before its reuse
    }

    const float inv0 = 1.0f / l_r[0];
    const float inv1 = 1.0f / l_r[1];
#pragma unroll
    for (int qg = 0; qg < 2; ++qg) {
        const float iv = qg ? inv1 : inv0;
        const int t = qw + qg * 16 + lr;
#pragma unroll
        for (int dg = 0; dg < 8; ++dg) {
            const int col = head * 128 + dg * 16 + lg * 4;
            float v0 = oacc[qg][dg][0] * iv, v1 = oacc[qg][dg][1] * iv;
            float v2 = oacc[qg][dg][2] * iv, v3 = oacc[qg][dg][3] * iv;
            unsigned short h0, h1, h2, h3, l0, l1, l2, l3;
            fsplit(v0, h0, l0); fsplit(v1, h1, l1); fsplit(v2, h2, l2); fsplit(v3, h3, l3);
            u16x4 hh = {h0, h1, h2, h3};
            u16x4 ll = {l0, l1, l2, l3};
            *(u16x4*)(AOh + (size_t)t * 2048 + col) = hh;
            *(u16x4*)(AOl + (size_t)t * 2048 + col) = ll;
        }
    }
}

// ---------------------------------------------------------------------------
// gated product: p = g * u (g pre-silu'd by GEMM epilogue), split output
__global__ __launch_bounds__(256) void mulsplit_k(const float* __restrict__ gu,
                                                  unsigned short* __restrict__ ph,
                                                  unsigned short* __restrict__ pl) {
    const int c4 = blockIdx.x * 256 + threadIdx.x;  // 0..767
    const int row = blockIdx.y;
    const float* base = gu + (size_t)row * 6144;
    float4 g = *(const float4*)(base + c4 * 4);
    float4 u = *(const float4*)(base + 3072 + c4 * 4);
    float p0 = g.x * u.x, p1 = g.y * u.y, p2 = g.z * u.z, p3 = g.w * u.w;
    unsigned short h0, h1, h2, h3, l0, l1, l2, l3;
    fsplit(p0, h0, l0); fsplit(p1, h1, l1); fsplit(p2, h2, l2); fsplit(p3, h3, l3);
    u16x4 hh = {h0, h1, h2, h3};
    u16x4 ll = {l0, l1, l2, l3};
    *(u16x4*)(ph + (size_t)row * 3072 + c4 * 4) = hh;
    *(u16x4*)(pl + (size_t)row * 3072 + c4 * 4) = ll;
}

// ---------------------------------------------------------------------------
extern "C" void kernel_launch(void* const* d_in, const int* in_sizes, int n_in,
                              void* d_out, int out_size, void* d_ws, size_t ws_size,
                              hipStream_t stream) {
    const float* emb = (const float*)d_in[0];
    const float* ln1 = (const float*)d_in[1];
    const float* qw  = (const float*)d_in[2];
    const float* kw  = (const float*)d_in[3];
    const float* vw  = (const float*)d_in[4];
    const float* qn  = (const float*)d_in[5];
    const float* kn  = (const float*)d_in[6];
    const float* ow  = (const float*)d_in[7];
    const float* ln2 = (const float*)d_in[8];
    const float* gw  = (const float*)d_in[9];
    const float* uw  = (const float*)d_in[10];
    const float* dw  = (const float*)d_in[11];
    const float* nw  = (const float*)d_in[12];

    float* out  = (float*)d_out;
    float* keys = out + (size_t)SEQ * DMODEL;
    float* vals = keys + (size_t)LAYERS * NKV * SEQ * HDIM;

    // ws layout (total 113 MiB; gu aliases 16..64 MiB, ph/pl alias 64..88 MiB)
    char* W = (char*)d_ws;
    float* h             = (float*)(W);
    unsigned short* xh   = (unsigned short*)(W + (8ull << 20));
    unsigned short* xl   = (unsigned short*)(W + (12ull << 20));
    float* qbuf          = (float*)(W + (16ull << 20));
    float* kvbuf         = (float*)(W + (32ull << 20));
    unsigned short* qb16 = (unsigned short*)(W + (48ull << 20));
    unsigned short* kb16 = (unsigned short*)(W + (56ull << 20));
    unsigned short* vt16 = (unsigned short*)(W + (60ull << 20));
    unsigned short* aoh  = (unsigned short*)(W + (64ull << 20));
    unsigned short* aol  = (unsigned short*)(W + (72ull << 20));
    float* gu            = (float*)(W + (16ull << 20));           // alias
    unsigned short* ph   = (unsigned short*)(W + (64ull << 20));  // alias
    unsigned short* pl   = (unsigned short*)(W + (76ull << 20));  // alias
    unsigned short* wh   = (unsigned short*)(W + (88ull << 20));
    unsigned short* wl   = (unsigned short*)(W + (100ull << 20));
    float* cosT          = (float*)(W + (112ull << 20));
    float* sinT          = cosT + SEQ * 64;

    hipMemcpyAsync(h, emb, sizeof(float) * SEQ * DMODEL, hipMemcpyDeviceToDevice, stream);
    rope_init_k<<<SEQ, 64, 0, stream>>>(cosT, sinT);

    for (int i = 0; i < LAYERS; ++i) {
        float* keys_i = keys + (size_t)i * NKV * SEQ * HDIM;
        float* vals_i = vals + (size_t)i * NKV * SEQ * HDIM;
        // ln1 -> x (split)
        rms_k<true><<<SEQ, 256, 0, stream>>>(h, ln1 + (size_t)i * DMODEL, nullptr, xh, xl);
        // q proj
        convert_w_k<<<2048, 256, 0, stream>>>(qw + (size_t)i * 2097152, wh, wl, 524288);
        gemm_sp<128, false><<<dim3(16, 16), 256, 0, stream>>>(xh, xl, wh, wl, qbuf, 2048, 1024, 0);
        // k,v proj fused (B rows 0..1023 = k_w, 1024..2047 = v_w)
        convert_w_k<<<1024, 256, 0, stream>>>(kw + (size_t)i * 1048576, wh, wl, 262144);
        convert_w_k<<<1024, 256, 0, stream>>>(vw + (size_t)i * 1048576, wh + 1048576, wl + 1048576, 262144);
        gemm_sp<128, false><<<dim3(16, 16), 256, 0, stream>>>(xh, xl, wh, wl, kvbuf, 2048, 1024, 0);
        // qk-norm + rope + layout
        qkv_post_k<<<SEQ * 32 / 4, 256, 0, stream>>>(qbuf, kvbuf, qn + (size_t)i * HDIM,
                                                     kn + (size_t)i * HDIM, cosT, sinT,
                                                     qb16, keys_i, kb16, vals_i);
        vtrans_k<<<dim3(SEQ / 32, HDIM / 32, NKV), 256, 0, stream>>>(vals_i, vt16);
        attn_k<<<dim3(SEQ / 64, NH), 128, 0, stream>>>(qb16, kb16, vt16, aoh, aol);
        // o proj (accumulate into h), BM=64 for full-chip grid (8x32=256 blocks)
        convert_w_k<<<2048, 256, 0, stream>>>(ow + (size_t)i * 2097152, wh, wl, 524288);
        gemm_sp<64, true><<<dim3(8, 32), 256, 0, stream>>>(aoh, aol, wh, wl, h, 1024, 2048, 0);
        // ln2 -> x (split)
        rms_k<true><<<SEQ, 256, 0, stream>>>(h, ln2 + (size_t)i * DMODEL, nullptr, xh, xl);
        // gate+up fused (rows 0..3071 = gate w/ silu, 3072..6143 = up)
        convert_w_k<<<3072, 256, 0, stream>>>(gw + (size_t)i * 3145728, wh, wl, 786432);
        convert_w_k<<<3072, 256, 0, stream>>>(uw + (size_t)i * 3145728, wh + 3145728, wl + 3145728, 786432);
        gemm_sp<128, false><<<dim3(48, 16), 256, 0, stream>>>(xh, xl, wh, wl, gu, 6144, 1024, 3072);
        mulsplit_k<<<dim3(3, SEQ), 256, 0, stream>>>(gu, ph, pl);
        // down proj (accumulate into h), BM=64
        convert_w_k<<<3072, 256, 0, stream>>>(dw + (size_t)i * 3145728, wh, wl, 786432);
        gemm_sp<64, true><<<dim3(8, 32), 256, 0, stream>>>(ph, pl, wh, wl, h, 1024, 3072, 0);
    }
    // final norm -> hs
    rms_k<false><<<SEQ, 256, 0, stream>>>(h, nw, out, nullptr, nullptr);
}

// Round 6
// 2241.413 us; speedup vs baseline: 4.4140x; 1.2272x over previous
//
#include <hip/hip_runtime.h>
#include <hip/hip_bf16.h>
#include <math.h>

#define LAYERS 5
#define DMODEL 1024
#define NH 16
#define NKV 8
#define HDIM 128
#define FFD 3072
#define SEQ 2048
#define RMS_EPS 1e-6f
// ATT_SCALE * log2(e):  0.08838834764831845 * 1.4426950408889634
#define SC2 0.12753292444440332f
#define NEGINF (-1e30f)

typedef __attribute__((ext_vector_type(8))) short bf16x8;
typedef __attribute__((ext_vector_type(4))) float f32x4;
typedef __attribute__((ext_vector_type(4))) unsigned short u16x4;

__device__ __forceinline__ unsigned short f2bf(float x) {
    unsigned int u = __float_as_uint(x);
    u = (u + 0x7fffu + ((u >> 16) & 1u)) >> 16;
    return (unsigned short)u;
}
__device__ __forceinline__ float bf2f(unsigned short b) {
    return __uint_as_float(((unsigned int)b) << 16);
}
__device__ __forceinline__ void fsplit(float x, unsigned short &h, unsigned short &l) {
    h = f2bf(x);
    l = f2bf(x - bf2f(h));
}

// ---------------------------------------------------------------------------
// RoPE tables (T x 64)
__global__ void rope_init_k(float* __restrict__ cosT, float* __restrict__ sinT) {
    int t = blockIdx.x;
    int j = threadIdx.x;  // 0..63
    double inv = pow(1.0e6, -((double)j) / 64.0);
    float angf = (float)t * (float)inv;
    double ang = (double)angf;
    cosT[t * 64 + j] = (float)cos(ang);
    sinT[t * 64 + j] = (float)sin(ang);
}

// ---------------------------------------------------------------------------
// RMSNorm over D=1024. SPLIT: write bf16 hi/lo pair; else fp32.
template <bool SPLIT>
__global__ __launch_bounds__(256) void rms_k(const float* __restrict__ in,
                                             const float* __restrict__ w,
                                             float* __restrict__ outf,
                                             unsigned short* __restrict__ oh,
                                             unsigned short* __restrict__ ol) {
    __shared__ float red[4];
    const int row = blockIdx.x;
    const int t = threadIdx.x;
    const float* p = in + (size_t)row * DMODEL;
    float4 v = *(const float4*)(p + t * 4);
    float ss = v.x * v.x + v.y * v.y + v.z * v.z + v.w * v.w;
#pragma unroll
    for (int off = 32; off >= 1; off >>= 1) ss += __shfl_xor(ss, off);
    if ((t & 63) == 0) red[t >> 6] = ss;
    __syncthreads();
    float tot = red[0] + red[1] + red[2] + red[3];
    float scale = rsqrtf(tot * (1.0f / DMODEL) + RMS_EPS);
    float4 w4 = *(const float4*)(w + t * 4);
    float o0 = v.x * scale * w4.x;
    float o1 = v.y * scale * w4.y;
    float o2 = v.z * scale * w4.z;
    float o3 = v.w * scale * w4.w;
    if (SPLIT) {
        unsigned short h0, h1, h2, h3, l0, l1, l2, l3;
        fsplit(o0, h0, l0); fsplit(o1, h1, l1); fsplit(o2, h2, l2); fsplit(o3, h3, l3);
        u16x4 hh = {h0, h1, h2, h3};
        u16x4 ll = {l0, l1, l2, l3};
        *(u16x4*)(oh + (size_t)row * DMODEL + t * 4) = hh;
        *(u16x4*)(ol + (size_t)row * DMODEL + t * 4) = ll;
    } else {
        float4 o = {o0, o1, o2, o3};
        *(float4*)(outf + (size_t)row * DMODEL + t * 4) = o;
    }
}

// ---------------------------------------------------------------------------
// fp32 -> bf16 hi/lo split (weights), float4 granularity
__global__ __launch_bounds__(256) void convert_w_k(const float* __restrict__ src,
                                                   unsigned short* __restrict__ hi,
                                                   unsigned short* __restrict__ lo,
                                                   int n4) {
    int i = blockIdx.x * 256 + threadIdx.x;
    if (i >= n4) return;
    float4 v = ((const float4*)src)[i];
    unsigned short h0, h1, h2, h3, l0, l1, l2, l3;
    fsplit(v.x, h0, l0); fsplit(v.y, h1, l1); fsplit(v.z, h2, l2); fsplit(v.w, h3, l3);
    u16x4 hh = {h0, h1, h2, h3};
    u16x4 ll = {l0, l1, l2, l3};
    ((u16x4*)hi)[i] = hh;
    ((u16x4*)lo)[i] = ll;
}

// ---------------------------------------------------------------------------
// Split-precision bf16 MFMA GEMM v2:  C[m][n] (+)= act( sum_k A[m][k]*B[n][k] )
// A,B pre-split bf16 (hi/lo) row-major, leading dim K. Tile BM x 128, BK=32,
// 4 waves. acc = Al*Bh + Ah*Bl + Ah*Bh.
// Double-buffered LDS, global_load_lds width=16, counted vmcnt (never 0
// in-loop), raw s_barrier, setprio around MFMA cluster.
// SPLITK>1: blockIdx.z takes K-chunk, partials atomicAdd'ed into C (fp32).
template <int BM, bool ACC, int SPLITK>
__global__ __launch_bounds__(256, (BM == 64) ? 3 : 2) void gemm_sp(
    const unsigned short* __restrict__ Ah, const unsigned short* __restrict__ Al,
    const unsigned short* __restrict__ Bh, const unsigned short* __restrict__ Bl,
    float* __restrict__ C, int N, int K, int actsplit) {
    constexpr int WM = (BM == 128) ? 2 : 1;   // waves along M
    constexpr int WN = 4 / WM;                // waves along N
    constexpr int WNS = 128 / WN;             // wave N-extent (64 or 32)
    constexpr int NF = WNS / 16;              // N frags per wave (4 or 2)
    constexpr int AUNITS = BM * 4;            // 16B units per A buffer
    constexpr int AISS = BM / 64;             // A issues per lane (2 or 1)
    constexpr int SBUF = (AUNITS * 2 + 1024) * 16;  // bytes per K-step buffer
    __shared__ __align__(16) char lds[2 * SBUF];

    const int tid = threadIdx.x;
    const int lane = tid & 63, wave = tid >> 6;
    const int wm = (BM == 128) ? (wave >> 1) : 0;
    const int wn = (BM == 128) ? (wave & 1) : wave;
    const int lr = lane & 15, lg = lane >> 4;
    const int m0 = blockIdx.y * BM, n0 = blockIdx.x * 128;
    const int Kc = K / SPLITK;
    const int kbeg = (SPLITK > 1) ? blockIdx.z * Kc : 0;

    f32x4 zero = {0.f, 0.f, 0.f, 0.f};
    f32x4 acc[4][NF];
#pragma unroll
    for (int m = 0; m < 4; ++m)
#pragma unroll
        for (int n = 0; n < NF; ++n) acc[m][n] = zero;

    const int swz = (lr >> 1) & 3;  // frag-read octet swizzle

    auto stage = [&](int k0, int b) {
        char* ldsAh = lds + b * SBUF;
        char* ldsAl = ldsAh + AUNITS * 16;
        char* ldsBh = ldsAh + AUNITS * 32;
        char* ldsBl = ldsBh + 8192;
#pragma unroll
        for (int i = 0; i < AISS; ++i) {
            const int u = i * 256 + wave * 64 + lane;
            const int row = u >> 2, cs = u & 3;
            const int c = cs ^ ((row >> 1) & 3);
            const size_t goff = (size_t)(m0 + row) * K + k0 + c * 8;
            const int lbase = (i * 256 + wave * 64) * 16;
            __builtin_amdgcn_global_load_lds(
                (const __attribute__((address_space(1))) void*)(Ah + goff),
                (__attribute__((address_space(3))) void*)(ldsAh + lbase), 16, 0, 0);
            __builtin_amdgcn_global_load_lds(
                (const __attribute__((address_space(1))) void*)(Al + goff),
                (__attribute__((address_space(3))) void*)(ldsAl + lbase), 16, 0, 0);
        }
#pragma unroll
        for (int i = 0; i < 2; ++i) {
            const int u = i * 256 + wave * 64 + lane;
            const int row = u >> 2, cs = u & 3;
            const int c = cs ^ ((row >> 1) & 3);
            const size_t goff = (size_t)(n0 + row) * K + k0 + c * 8;
            const int lbase = (i * 256 + wave * 64) * 16;
            __builtin_amdgcn_global_load_lds(
                (const __attribute__((address_space(1))) void*)(Bh + goff),
                (__attribute__((address_space(3))) void*)(ldsBh + lbase), 16, 0, 0);
            __builtin_amdgcn_global_load_lds(
                (const __attribute__((address_space(1))) void*)(Bl + goff),
                (__attribute__((address_space(3))) void*)(ldsBl + lbase), 16, 0, 0);
        }
    };

    const int nsteps = Kc / 32;
    stage(kbeg, 0);
    for (int s = 0; s < nsteps; ++s) {
        const int cur = s & 1;
        if (s + 1 < nsteps) {
            stage(kbeg + (s + 1) * 32, cur ^ 1);
            // wait for current tile only; next tile's loads stay in flight
            if constexpr (AISS == 2) {
                asm volatile("s_waitcnt vmcnt(8)" ::: "memory");
            } else {
                asm volatile("s_waitcnt vmcnt(6)" ::: "memory");
            }
        } else {
            asm volatile("s_waitcnt vmcnt(0)" ::: "memory");
        }
        __builtin_amdgcn_s_barrier();

        char* ldsAh = lds + cur * SBUF;
        char* ldsAl = ldsAh + AUNITS * 16;
        char* ldsBh = ldsAh + AUNITS * 32;
        char* ldsBl = ldsBh + 8192;
        bf16x8 fAh[4], fAl[4], fBh[NF], fBl[NF];
#pragma unroll
        for (int m = 0; m < 4; ++m) {
            const int row = wm * 64 + m * 16 + lr;
            const int u = row * 4 + (lg ^ swz);
            fAh[m] = *(const bf16x8*)(ldsAh + u * 16);
            fAl[m] = *(const bf16x8*)(ldsAl + u * 16);
        }
#pragma unroll
        for (int n = 0; n < NF; ++n) {
            const int row = wn * WNS + n * 16 + lr;
            const int u = row * 4 + (lg ^ swz);
            fBh[n] = *(const bf16x8*)(ldsBh + u * 16);
            fBl[n] = *(const bf16x8*)(ldsBl + u * 16);
        }
        __builtin_amdgcn_s_setprio(1);
#pragma unroll
        for (int m = 0; m < 4; ++m)
#pragma unroll
            for (int n = 0; n < NF; ++n) {
                acc[m][n] = __builtin_amdgcn_mfma_f32_16x16x32_bf16(fAl[m], fBh[n], acc[m][n], 0, 0, 0);
                acc[m][n] = __builtin_amdgcn_mfma_f32_16x16x32_bf16(fAh[m], fBl[n], acc[m][n], 0, 0, 0);
                acc[m][n] = __builtin_amdgcn_mfma_f32_16x16x32_bf16(fAh[m], fBh[n], acc[m][n], 0, 0, 0);
            }
        __builtin_amdgcn_s_setprio(0);
        __builtin_amdgcn_s_barrier();  // reads of buf[cur] done before overwrite
    }
#pragma unroll
    for (int m = 0; m < 4; ++m) {
        const int row = m0 + wm * 64 + m * 16 + lg * 4;
#pragma unroll
        for (int n = 0; n < NF; ++n) {
            const int col = n0 + wn * WNS + n * 16 + lr;
            const bool act = col < actsplit;
            float* cp = C + (size_t)row * N + col;
#pragma unroll
            for (int j = 0; j < 4; ++j) {
                float v = acc[m][n][j];
                if (act) v = v / (1.0f + expf(-v));
                if (ACC) {
                    if (SPLITK > 1) atomicAdd(cp + (size_t)j * N, v);
                    else cp[(size_t)j * N] += v;
                } else {
                    cp[(size_t)j * N] = v;
                }
            }
        }
    }
}

// ---------------------------------------------------------------------------
// Post-QKV: qk-norm + rope; q -> bf16 [H][T][HD]; k -> keys fp32 + bf16 copy;
// v -> vals fp32. kvbuf is [T][2048]: k cols 0..1023, v cols 1024..2047.
__global__ __launch_bounds__(256) void qkv_post_k(
    const float* __restrict__ qbuf, const float* __restrict__ kvbuf,
    const float* __restrict__ qn, const float* __restrict__ kn,
    const float* __restrict__ cosT, const float* __restrict__ sinT,
    unsigned short* __restrict__ qb16, float* __restrict__ keys,
    unsigned short* __restrict__ kb16, float* __restrict__ vals) {
    const int r = blockIdx.x * 4 + (threadIdx.x >> 6);
    const int lane = threadIdx.x & 63;
    const int t = r >> 5, c = r & 31;
    if (c >= 24) {  // v: copy/transpose
        const int vh = c - 24;
        const float* src = kvbuf + (size_t)t * 2048 + 1024 + vh * 128;
        float* dst = vals + ((size_t)vh * SEQ + t) * 128;
        dst[lane] = src[lane];
        dst[lane + 64] = src[lane + 64];
        return;
    }
    const float* src;
    const float* nw;
    if (c < 16) { src = qbuf + (size_t)t * 2048 + c * 128; nw = qn; }
    else        { src = kvbuf + (size_t)t * 2048 + (c - 16) * 128; nw = kn; }
    float x1 = src[lane], x2 = src[lane + 64];
    float ss = x1 * x1 + x2 * x2;
#pragma unroll
    for (int off = 32; off >= 1; off >>= 1) ss += __shfl_xor(ss, off);
    float scale = rsqrtf(ss * (1.0f / HDIM) + RMS_EPS);
    float xn1 = x1 * scale * nw[lane];
    float xn2 = x2 * scale * nw[lane + 64];
    float cc = cosT[t * 64 + lane], sv = sinT[t * 64 + lane];
    float o1 = xn1 * cc - xn2 * sv;
    float o2 = xn2 * cc + xn1 * sv;
    if (c < 16) {
        unsigned short* dst = qb16 + ((size_t)c * SEQ + t) * 128;
        dst[lane] = f2bf(o1);
        dst[lane + 64] = f2bf(o2);
    } else {
        const int kh = c - 16;
        float* kd = keys + ((size_t)kh * SEQ + t) * 128;
        kd[lane] = o1;
        kd[lane + 64] = o2;
        unsigned short* kb = kb16 + ((size_t)kh * SEQ + t) * 128;
        kb[lane] = f2bf(o1);
        kb[lane + 64] = f2bf(o2);
    }
}

// ---------------------------------------------------------------------------
// V transpose: vals fp32 [KV][T][HD] -> vt bf16 [KV][HD][T]
__global__ __launch_bounds__(256) void vtrans_k(const float* __restrict__ vals,
                                                unsigned short* __restrict__ vt) {
    __shared__ float tile[32][33];
    const int t0 = blockIdx.x * 32, d0 = blockIdx.y * 32, kvh = blockIdx.z;
    const int a = threadIdx.x >> 3, b4 = (threadIdx.x & 7) * 4;
    const float4 v = *(const float4*)(vals + ((size_t)kvh * SEQ + t0 + a) * 128 + d0 + b4);
    tile[a][b4] = v.x; tile[a][b4 + 1] = v.y; tile[a][b4 + 2] = v.z; tile[a][b4 + 3] = v.w;
    __syncthreads();
    u16x4 o = {f2bf(tile[b4][a]), f2bf(tile[b4 + 1][a]), f2bf(tile[b4 + 2][a]), f2bf(tile[b4 + 3][a])};
    *(u16x4*)(vt + ((size_t)kvh * HDIM + d0 + a) * SEQ + t0 + b4) = o;
}

// ---------------------------------------------------------------------------
// Flash attention v2 (unchanged from round 5): bf16 MFMA, causal, KVBLK=64,
// double-buffered global_load_lds staging with counted vmcnt + raw barriers.
__global__ __launch_bounds__(128, 1) void attn_k(
    const unsigned short* __restrict__ Qb, const unsigned short* __restrict__ Kb,
    const unsigned short* __restrict__ Vt,
    unsigned short* __restrict__ AOh, unsigned short* __restrict__ AOl) {
    __shared__ __align__(16) char lds[73728];
    const int tid = threadIdx.x;
    const int wave = tid >> 6, lane = tid & 63;
    const int lr = lane & 15, lg = lane >> 4;
    const int head = blockIdx.y, kvh = head >> 1;
    const int qtile = blockIdx.x;
    const int qw = qtile * 64 + wave * 32;
    char* Pw = lds + 65536 + wave * 4096;
    const size_t kbase = (size_t)kvh * SEQ;          // K rows base
    const size_t vtb = (size_t)kvh * HDIM;           // V^T rows base

    bf16x8 qf[2][4];
#pragma unroll
    for (int qg = 0; qg < 2; ++qg)
#pragma unroll
        for (int ds = 0; ds < 4; ++ds)
            qf[qg][ds] = *(const bf16x8*)(Qb + ((size_t)head * SEQ + qw + qg * 16 + lr) * 128 + ds * 32 + lg * 8);

    f32x4 zero = {0.f, 0.f, 0.f, 0.f};
    f32x4 oacc[2][8];
#pragma unroll
    for (int qg = 0; qg < 2; ++qg)
#pragma unroll
        for (int dg = 0; dg < 8; ++dg) oacc[qg][dg] = zero;
    float m_r[2] = {NEGINF, NEGINF};
    float l_r[2] = {0.f, 0.f};

    auto stage = [&](int k0, int b) {
        const int kOff = b ? 16384 : 0;
        const int vOff = b ? 49152 : 32768;
#pragma unroll
        for (int i = 0; i < 8; ++i) {
            const int L = (i * 2 + wave) * 64 + lane;
            const int row = L >> 4, u = L & 15;
            const unsigned short* src = Kb + (kbase + k0 + row) * 128 + ((u ^ (row & 7)) << 3);
            __builtin_amdgcn_global_load_lds(
                (const __attribute__((address_space(1))) void*)src,
                (__attribute__((address_space(3))) void*)(lds + kOff + ((i * 2 + wave) << 10)), 16, 0, 0);
        }
#pragma unroll
        for (int i = 0; i < 8; ++i) {
            const int L = (i * 2 + wave) * 64 + lane;
            const int row = L >> 3, u = L & 7;
            const unsigned short* src = Vt + (vtb + row) * 2048 + k0 + ((u ^ (row & 7)) << 3);
            __builtin_amdgcn_global_load_lds(
                (const __attribute__((address_space(1))) void*)src,
                (__attribute__((address_space(3))) void*)(lds + vOff + ((i * 2 + wave) << 10)), 16, 0, 0);
        }
    };

    const int nsteps = qtile + 1;
    stage(0, 0);
    for (int s = 0; s < nsteps; ++s) {
        const int cur = s & 1;
        const int k0 = s * 64;
        if (s + 1 < nsteps) {
            stage((s + 1) * 64, cur ^ 1);
            asm volatile("s_waitcnt vmcnt(16)" ::: "memory");
        } else {
            asm volatile("s_waitcnt vmcnt(0)" ::: "memory");
        }
        __builtin_amdgcn_s_barrier();

        const int kOff = cur ? 16384 : 0;
        const int vOff = cur ? 49152 : 32768;
        f32x4 S[4][2];
#pragma unroll
        for (int kg = 0; kg < 4; ++kg) { S[kg][0] = zero; S[kg][1] = zero; }
        __builtin_amdgcn_s_setprio(1);
#pragma unroll
        for (int ds = 0; ds < 4; ++ds) {
#pragma unroll
            for (int kg = 0; kg < 4; ++kg) {
                const int krow = kg * 16 + lr;
                bf16x8 kf = *(const bf16x8*)(lds + kOff + ((krow * 16 + ((ds * 4 + lg) ^ (krow & 7))) << 4));
                S[kg][0] = __builtin_amdgcn_mfma_f32_16x16x32_bf16(kf, qf[0][ds], S[kg][0], 0, 0, 0);
                S[kg][1] = __builtin_amdgcn_mfma_f32_16x16x32_bf16(kf, qf[1][ds], S[kg][1], 0, 0, 0);
            }
        }
        __builtin_amdgcn_s_setprio(0);
        const bool diag = (s == qtile);
#pragma unroll
        for (int qg = 0; qg < 2; ++qg) {
            const int q = qw + qg * 16 + lr;
            float p[4][4];
            float mm = NEGINF;
#pragma unroll
            for (int kg = 0; kg < 4; ++kg)
#pragma unroll
                for (int j = 0; j < 4; ++j) {
                    float sv = S[kg][qg][j] * SC2;
                    if (diag) {
                        const int kk = k0 + kg * 16 + lg * 4 + j;
                        sv = (kk <= q) ? sv : NEGINF;
                    }
                    p[kg][j] = sv;
                    mm = fmaxf(mm, sv);
                }
            mm = fmaxf(mm, __shfl_xor(mm, 16));
            mm = fmaxf(mm, __shfl_xor(mm, 32));
            if (!__all(mm <= m_r[qg] + 11.5f)) {  // defer-max
                const float mnew = fmaxf(m_r[qg], mm);
                const float alpha = exp2f(m_r[qg] - mnew);
                l_r[qg] *= alpha;
#pragma unroll
                for (int dg = 0; dg < 8; ++dg) oacc[qg][dg] *= alpha;
                m_r[qg] = mnew;
            }
            float ps = 0.f;
            const int qloc = qg * 16 + lr;
#pragma unroll
            for (int kg = 0; kg < 4; ++kg) {
                u16x4 pw;
#pragma unroll
                for (int j = 0; j < 4; ++j) {
                    const float e = exp2f(p[kg][j] - m_r[qg]);
                    ps += e;
                    pw[j] = f2bf(e);
                }
                *(u16x4*)(Pw + ((qloc * 128 + kg * 32 + lg * 8) ^ ((lr & 7) << 4))) = pw;
            }
            ps += __shfl_xor(ps, 16);
            ps += __shfl_xor(ps, 32);
            l_r[qg] += ps;
        }
        asm volatile("s_waitcnt lgkmcnt(0)" ::: "memory");
        bf16x8 pf[2][2];
#pragma unroll
        for (int qg = 0; qg < 2; ++qg)
#pragma unroll
            for (int ks = 0; ks < 2; ++ks) {
                const int qloc = qg * 16 + lr;
                pf[qg][ks] = *(const bf16x8*)(Pw + ((qloc * 128 + ks * 64 + lg * 16) ^ ((lr & 7) << 4)));
            }
        __builtin_amdgcn_s_setprio(1);
#pragma unroll
        for (int dg = 0; dg < 8; ++dg) {
            const int drow = dg * 16 + lr;
#pragma unroll
            for (int ks = 0; ks < 2; ++ks) {
                bf16x8 vf = *(const bf16x8*)(lds + vOff + ((drow * 8 + ((ks * 4 + lg) ^ (drow & 7))) << 4));
                oacc[0][dg] = __builtin_amdgcn_mfma_f32_16x16x32_bf16(vf, pf[0][ks], oacc[0][dg], 0, 0, 0);
                oacc[1][dg] = __builtin_amdgcn_mfma_f32_16x16x32_bf16(vf, pf[1][ks], oacc[1][dg], 0, 0, 0);
            }
        }
        __builtin_amdgcn_s_setprio(0);
        __builtin_amdgcn_s_barrier();
    }

    const float inv0 = 1.0f / l_r[0];
    const float inv1 = 1.0f / l_r[1];
#pragma unroll
    for (int qg = 0; qg < 2; ++qg) {
        const float iv = qg ? inv1 : inv0;
        const int t = qw + qg * 16 + lr;
#pragma unroll
        for (int dg = 0; dg < 8; ++dg) {
            const int col = head * 128 + dg * 16 + lg * 4;
            float v0 = oacc[qg][dg][0] * iv, v1 = oacc[qg][dg][1] * iv;
            float v2 = oacc[qg][dg][2] * iv, v3 = oacc[qg][dg][3] * iv;
            unsigned short h0, h1, h2, h3, l0, l1, l2, l3;
            fsplit(v0, h0, l0); fsplit(v1, h1, l1); fsplit(v2, h2, l2); fsplit(v3, h3, l3);
            u16x4 hh = {h0, h1, h2, h3};
            u16x4 ll = {l0, l1, l2, l3};
            *(u16x4*)(AOh + (size_t)t * 2048 + col) = hh;
            *(u16x4*)(AOl + (size_t)t * 2048 + col) = ll;
        }
    }
}

// ---------------------------------------------------------------------------
// gated product: p = g * u (g pre-silu'd by GEMM epilogue), split output
__global__ __launch_bounds__(256) void mulsplit_k(const float* __restrict__ gu,
                                                  unsigned short* __restrict__ ph,
                                                  unsigned short* __restrict__ pl) {
    const int c4 = blockIdx.x * 256 + threadIdx.x;  // 0..767
    const int row = blockIdx.y;
    const float* base = gu + (size_t)row * 6144;
    float4 g = *(const float4*)(base + c4 * 4);
    float4 u = *(const float4*)(base + 3072 + c4 * 4);
    float p0 = g.x * u.x, p1 = g.y * u.y, p2 = g.z * u.z, p3 = g.w * u.w;
    unsigned short h0, h1, h2, h3, l0, l1, l2, l3;
    fsplit(p0, h0, l0); fsplit(p1, h1, l1); fsplit(p2, h2, l2); fsplit(p3, h3, l3);
    u16x4 hh = {h0, h1, h2, h3};
    u16x4 ll = {l0, l1, l2, l3};
    *(u16x4*)(ph + (size_t)row * 3072 + c4 * 4) = hh;
    *(u16x4*)(pl + (size_t)row * 3072 + c4 * 4) = ll;
}

// ---------------------------------------------------------------------------
extern "C" void kernel_launch(void* const* d_in, const int* in_sizes, int n_in,
                              void* d_out, int out_size, void* d_ws, size_t ws_size,
                              hipStream_t stream) {
    const float* emb = (const float*)d_in[0];
    const float* ln1 = (const float*)d_in[1];
    const float* qw  = (const float*)d_in[2];
    const float* kw  = (const float*)d_in[3];
    const float* vw  = (const float*)d_in[4];
    const float* qn  = (const float*)d_in[5];
    const float* kn  = (const float*)d_in[6];
    const float* ow  = (const float*)d_in[7];
    const float* ln2 = (const float*)d_in[8];
    const float* gw  = (const float*)d_in[9];
    const float* uw  = (const float*)d_in[10];
    const float* dw  = (const float*)d_in[11];
    const float* nw  = (const float*)d_in[12];

    float* out  = (float*)d_out;
    float* keys = out + (size_t)SEQ * DMODEL;
    float* vals = keys + (size_t)LAYERS * NKV * SEQ * HDIM;

    // ws layout (total 113 MiB; gu aliases 16..64 MiB, ph/pl alias 64..88 MiB)
    char* W = (char*)d_ws;
    float* h             = (float*)(W);
    unsigned short* xh   = (unsigned short*)(W + (8ull << 20));
    unsigned short* xl   = (unsigned short*)(W + (12ull << 20));
    float* qbuf          = (float*)(W + (16ull << 20));
    float* kvbuf         = (float*)(W + (32ull << 20));
    unsigned short* qb16 = (unsigned short*)(W + (48ull << 20));
    unsigned short* kb16 = (unsigned short*)(W + (56ull << 20));
    unsigned short* vt16 = (unsigned short*)(W + (60ull << 20));
    unsigned short* aoh  = (unsigned short*)(W + (64ull << 20));
    unsigned short* aol  = (unsigned short*)(W + (72ull << 20));
    float* gu            = (float*)(W + (16ull << 20));           // alias
    unsigned short* ph   = (unsigned short*)(W + (64ull << 20));  // alias
    unsigned short* pl   = (unsigned short*)(W + (76ull << 20));  // alias
    unsigned short* wh   = (unsigned short*)(W + (88ull << 20));
    unsigned short* wl   = (unsigned short*)(W + (100ull << 20));
    float* cosT          = (float*)(W + (112ull << 20));
    float* sinT          = cosT + SEQ * 64;

    hipMemcpyAsync(h, emb, sizeof(float) * SEQ * DMODEL, hipMemcpyDeviceToDevice, stream);
    rope_init_k<<<SEQ, 64, 0, stream>>>(cosT, sinT);

    for (int i = 0; i < LAYERS; ++i) {
        float* keys_i = keys + (size_t)i * NKV * SEQ * HDIM;
        float* vals_i = vals + (size_t)i * NKV * SEQ * HDIM;
        // ln1 -> x (split)
        rms_k<true><<<SEQ, 256, 0, stream>>>(h, ln1 + (size_t)i * DMODEL, nullptr, xh, xl);
        // q proj
        convert_w_k<<<2048, 256, 0, stream>>>(qw + (size_t)i * 2097152, wh, wl, 524288);
        gemm_sp<128, false, 1><<<dim3(16, 16), 256, 0, stream>>>(xh, xl, wh, wl, qbuf, 2048, 1024, 0);
        // k,v proj fused (B rows 0..1023 = k_w, 1024..2047 = v_w)
        convert_w_k<<<1024, 256, 0, stream>>>(kw + (size_t)i * 1048576, wh, wl, 262144);
        convert_w_k<<<1024, 256, 0, stream>>>(vw + (size_t)i * 1048576, wh + 1048576, wl + 1048576, 262144);
        gemm_sp<128, false, 1><<<dim3(16, 16), 256, 0, stream>>>(xh, xl, wh, wl, kvbuf, 2048, 1024, 0);
        // qk-norm + rope + layout
        qkv_post_k<<<SEQ * 32 / 4, 256, 0, stream>>>(qbuf, kvbuf, qn + (size_t)i * HDIM,
                                                     kn + (size_t)i * HDIM, cosT, sinT,
                                                     qb16, keys_i, kb16, vals_i);
        vtrans_k<<<dim3(SEQ / 32, HDIM / 32, NKV), 256, 0, stream>>>(vals_i, vt16);
        attn_k<<<dim3(SEQ / 64, NH), 128, 0, stream>>>(qb16, kb16, vt16, aoh, aol);
        // o proj (atomic-accumulate into h), BM=64, split-K=2 -> 512 blocks
        convert_w_k<<<2048, 256, 0, stream>>>(ow + (size_t)i * 2097152, wh, wl, 524288);
        gemm_sp<64, true, 2><<<dim3(8, 32, 2), 256, 0, stream>>>(aoh, aol, wh, wl, h, 1024, 2048, 0);
        // ln2 -> x (split)
        rms_k<true><<<SEQ, 256, 0, stream>>>(h, ln2 + (size_t)i * DMODEL, nullptr, xh, xl);
        // gate+up fused (rows 0..3071 = gate w/ silu, 3072..6143 = up)
        convert_w_k<<<3072, 256, 0, stream>>>(gw + (size_t)i * 3145728, wh, wl, 786432);
        convert_w_k<<<3072, 256, 0, stream>>>(uw + (size_t)i * 3145728, wh + 3145728, wl + 3145728, 786432);
        gemm_sp<128, false, 1><<<dim3(48, 16), 256, 0, stream>>>(xh, xl, wh, wl, gu, 6144, 1024, 3072);
        mulsplit_k<<<dim3(3, SEQ), 256, 0, stream>>>(gu, ph, pl);
        // down proj (atomic-accumulate into h), BM=64, split-K=2 -> 512 blocks
        convert_w_k<<<3072, 256, 0, stream>>>(dw + (size_t)i * 3145728, wh, wl, 786432);
        gemm_sp<64, true, 2><<<dim3(8, 32, 2), 256, 0, stream>>>(ph, pl, wh, wl, h, 1024, 3072, 0);
    }
    // final norm -> hs
    rms_k<false><<<SEQ, 256, 0, stream>>>(h, nw, out, nullptr, nullptr);
}